// Round 8
// baseline (188.699 us; speedup 1.0000x reference)
//
#include <hip/hip_runtime.h>
#include <math.h>

// Problem constants (fixed by reference)
#define BDIM 8
#define TDIM 2048
#define CDIM 256
#define HDIM 8
#define DDIM 32
#define TP   (TDIM + 2)   // padded time (halo row above and below, zeroed)

typedef __attribute__((ext_vector_type(8))) short bf16x8;   // MFMA A/B frag (4 VGPR)
typedef __attribute__((ext_vector_type(4))) float f32x4;    // MFMA C/D frag

#if __has_builtin(__builtin_amdgcn_exp2f)
#define EXP2(x) __builtin_amdgcn_exp2f(x)
#else
#define EXP2(x) exp2f(x)
#endif

// pack two f32 -> one dword of two bf16 (round-half-up: +0x8000 then v_perm)
__device__ __forceinline__ unsigned pk2(float lo, float hi) {
    union { float f; unsigned u; } a, b;
    a.f = lo; b.f = hi;
    return __builtin_amdgcn_perm(b.u + 0x8000u, a.u + 0x8000u, 0x07060302u);
}
// truncating pack (1 op). For p >= 0 the <=0.8% downward bias cancels between
// softmax numerator and denominator (l is summed from the SAME bf16 values).
__device__ __forceinline__ unsigned pk2t(float lo, float hi) {
    union { float f; unsigned u; } a, b;
    a.f = lo; b.f = hi;
    return __builtin_amdgcn_perm(b.u, a.u, 0x07060302u);
}
__device__ __forceinline__ short bf1(float v) {
    union { float f; unsigned u; } a; a.f = v;
    return (short)((a.u + 0x8000u) >> 16);
}
// async global->LDS, 16B per lane (dest must be wave-uniform base + lane*16)
__device__ __forceinline__ void gld16(const short* g, short* l) {
    __builtin_amdgcn_global_load_lds((const __attribute__((address_space(1))) void*)g,
                                     (__attribute__((address_space(3))) void*)l, 16, 0, 0);
}

#define XBLK 832   // prep: blocks doing x-convert + halos
#define WBLK 192   // prep: blocks doing LDS-tiled weight transpose (12 pairs x 16)

// ---------------------------------------------------------------------------
// Prep: x -> bf16 padded xbfp[B][TP][C] (halos zero); weights -> bf16 W^T
// (row=co, col=k=dt*256+ci) via LDS-tiled transpose (coalesced both sides).
// ---------------------------------------------------------------------------
__global__ __launch_bounds__(256) void prep_kernel(
    const float* __restrict__ x,
    const float* __restrict__ Wq, const float* __restrict__ Wk,
    const float* __restrict__ Wv, const float* __restrict__ Wo,
    short* __restrict__ xbfp, short* __restrict__ cp,
    short* __restrict__ wcat, short* __restrict__ wot)
{
    const int tid = threadIdx.x;
    if (blockIdx.x < XBLK) {
        const int NX = BDIM * TDIM * 64;    // float4 chunks of x
        const int NH = 4096;                // halo dwords (xbfp + cp)
        unsigned* xw = (unsigned*)xbfp;
        unsigned* cw = (unsigned*)cp;
        for (int i = blockIdx.x * 256 + tid; i < NX + NH; i += XBLK * 256) {
            if (i < NX) {
                const int bt = i >> 6, c4 = i & 63;
                const int b = bt >> 11, t = bt & 2047;
                const float4 f = *(const float4*)(x + (size_t)bt * 256 + c4 * 4);
                const size_t wo_ = (size_t)(b * TP + t + 1) * 128 + c4 * 2;
                xw[wo_]     = pk2(f.x, f.y);
                xw[wo_ + 1] = pk2(f.z, f.w);
            } else {
                const int hz = i - NX;
                const int half = hz >> 11, z = hz & 2047;
                const int b = z >> 8, r = (z >> 7) & 1, wofs = z & 127;
                const size_t w_ = ((size_t)b * TP + (size_t)r * (TP - 1)) * 128 + wofs;
                if (half == 0) xw[w_] = 0u; else cw[w_] = 0u;
            }
        }
    } else {
        // weight transpose: 12 (dt,mat) pairs x 16 subtiles of 64ci x 64co
        __shared__ float xs[64][65];
        const int wb = blockIdx.x - XBLK;
        const int pair = wb >> 4, sub = wb & 15;
        const int dt = pair >> 2, mat = pair & 3;        // mat: 0=q 1=k 2=v 3=o
        const int ci0 = (sub >> 2) * 64, co0 = (sub & 3) * 64;
        const float* W = mat == 0 ? Wq : mat == 1 ? Wk : mat == 2 ? Wv : Wo;
        const float* src = W + dt * 65536 + (size_t)ci0 * 256 + co0;
        for (int idx = tid; idx < 4096; idx += 256) {
            const int r = idx >> 6, c = idx & 63;
            xs[r][c] = src[(size_t)r * 256 + c];
        }
        __syncthreads();
        short* dstbase = (mat < 3) ? (wcat + (size_t)(mat * 256 + co0) * 768)
                                   : (wot + (size_t)co0 * 768);
        for (int idx = tid; idx < 512; idx += 256) {
            const int co_l = idx >> 3, ci_l = (idx & 7) * 8;
            uint4 u;
            u.x = pk2(xs[ci_l + 0][co_l], xs[ci_l + 1][co_l]);
            u.y = pk2(xs[ci_l + 2][co_l], xs[ci_l + 3][co_l]);
            u.z = pk2(xs[ci_l + 4][co_l], xs[ci_l + 5][co_l]);
            u.w = pk2(xs[ci_l + 6][co_l], xs[ci_l + 7][co_l]);
            *(uint4*)(dstbase + (size_t)co_l * 768 + dt * 256 + ci0 + ci_l) = u;
        }
    }
}

// ---------------------------------------------------------------------------
// QKV conv as double-buffered MFMA GEMM (m97 structure).
// Result transposed: A = W rows (m=co_cat), B = x rows (n=t).
// Block 256 thr = 4 waves; tile 128 co x 128 t; BK=32 (k = dt*256+ci, chunks
// never straddle dt). grid (128 t-tiles, 6 co-tiles); blockIdx.y>>1 = q/k/v.
// V-epilogue: R6 direct scatter stores (known-good).
// ---------------------------------------------------------------------------
__global__ __launch_bounds__(256) void gemm_qkv(
    const short* __restrict__ xbfp, const short* __restrict__ wcat,
    const float* __restrict__ bq, const float* __restrict__ bk,
    const float* __restrict__ bv,
    short* __restrict__ qo, short* __restrict__ ko, short* __restrict__ vt2)
{
    __shared__ short As[2][4096];
    __shared__ short Bs[2][4096];
    const int tid = threadIdx.x;
    const int wv = tid >> 6, lane = tid & 63, quad = lane >> 4, col = lane & 15;
    const int bx = blockIdx.x;
    const int b = bx >> 4, t0 = (bx & 15) * 128;
    const int by = blockIdx.y;
    const int qkv = by >> 1;
    const int m0 = by * 128;

    const short* wA = wcat + (size_t)m0 * 768;
    const short* xB = xbfp + ((size_t)b * TP + t0) * CDIM;
    const int r0 = tid >> 2, s0 = (tid & 3) * 8;   // chunk row / in-row offset

#define STAGE_Q(kk, bsel) do {                                                  \
    const int dt_ = (kk) >> 3, ci0_ = ((kk) & 7) * 32, k0_ = (kk) * 32;         \
    gld16(wA + (size_t)r0 * 768 + k0_ + s0,        &As[bsel][tid * 8]);         \
    gld16(wA + (size_t)(r0 + 64) * 768 + k0_ + s0, &As[bsel][tid * 8 + 2048]);  \
    gld16(xB + (size_t)(r0 + dt_) * 256 + ci0_ + s0,      &Bs[bsel][tid * 8]);  \
    gld16(xB + (size_t)(r0 + 64 + dt_) * 256 + ci0_ + s0, &Bs[bsel][tid * 8 + 2048]); \
} while (0)

    STAGE_Q(0, 0);

    const float* bias = qkv == 0 ? bq : qkv == 1 ? bk : bv;
    f32x4 acc[4][4];
#pragma unroll
    for (int mt = 0; mt < 4; ++mt) {
        const int cb = ((m0 + (wv & 1) * 64 + mt * 16) & 255) + quad * 4;
        const float4 b4 = *(const float4*)(bias + cb);
#pragma unroll
        for (int nt = 0; nt < 4; ++nt) acc[mt][nt] = (f32x4){b4.x, b4.y, b4.z, b4.w};
    }

    int bsel = 0;
    for (int kk = 0; kk < 24; ++kk) {
        __syncthreads();
        if (kk < 23) STAGE_Q(kk + 1, bsel ^ 1);
        const short* Ab = &As[bsel][((wv & 1) * 64 + col) * 32 + quad * 8];
        const short* Bb = &Bs[bsel][((wv >> 1) * 64 + col) * 32 + quad * 8];
        bf16x8 af[4], bfr[4];
#pragma unroll
        for (int i = 0; i < 4; ++i) {
            af[i]  = *(const bf16x8*)(Ab + i * 512);
            bfr[i] = *(const bf16x8*)(Bb + i * 512);
        }
#pragma unroll
        for (int mt = 0; mt < 4; ++mt)
#pragma unroll
            for (int nt = 0; nt < 4; ++nt)
                acc[mt][nt] = __builtin_amdgcn_mfma_f32_16x16x32_bf16(af[mt], bfr[nt], acc[mt][nt], 0, 0, 0);
        bsel ^= 1;
    }

    const float qs = 0.25503000508221157f;   // log2(e)/sqrt(32)
#pragma unroll
    for (int mt = 0; mt < 4; ++mt) {
        const int cocat = m0 + (wv & 1) * 64 + mt * 16 + quad * 4;
        const int co = cocat & 255;
        const int hh = co >> 5, d = co & 31;
        const size_t bh = (size_t)b * HDIM + hh;
#pragma unroll
        for (int nt = 0; nt < 4; ++nt) {
            const int t = t0 + (wv >> 1) * 64 + nt * 16 + col;
            const f32x4 a = acc[mt][nt];
            if (qkv == 0) {
                uint2 u = make_uint2(pk2(a[0] * qs, a[1] * qs), pk2(a[2] * qs, a[3] * qs));
                *(uint2*)(qo + (bh * TDIM + t) * DDIM + d) = u;
            } else if (qkv == 1) {
                uint2 u = make_uint2(pk2(a[0], a[1]), pk2(a[2], a[3]));
                *(uint2*)(ko + (bh * TDIM + t) * DDIM + d) = u;
            } else {
                const int kt = t >> 6, u6 = t & 63, kg = u6 >> 5, rr = u6 & 31;
                const int j = ((rr >> 4) << 2) | (rr & 3), qd = (rr >> 2) & 3;
                short* vb2 = vt2 + ((bh * 32 + kt) * 2 + kg) * 1024 + qd * 8 + j;
#pragma unroll
                for (int r = 0; r < 4; ++r) vb2[(d + r) * 32] = bf1(a[r]);
            }
        }
    }
#undef STAGE_Q
}

// ---------------------------------------------------------------------------
// Output conv + residual, same GEMM structure. A = Wot rows (m=co, M=256),
// B = ctx rows from padded cp (n=t). grid (128, 2). out = x + acc (+bo).
// ---------------------------------------------------------------------------
__global__ __launch_bounds__(256) void gemm_res(
    const short* __restrict__ cp, const short* __restrict__ wot,
    const float* __restrict__ bo, const float* __restrict__ x,
    float* __restrict__ out)
{
    __shared__ short As[2][4096];
    __shared__ short Bs[2][4096];
    const int tid = threadIdx.x;
    const int wv = tid >> 6, lane = tid & 63, quad = lane >> 4, col = lane & 15;
    const int bx = blockIdx.x;
    const int b = bx >> 4, t0 = (bx & 15) * 128;
    const int m0 = blockIdx.y * 128;

    const short* wA = wot + (size_t)m0 * 768;
    const short* cB = cp + ((size_t)b * TP + t0) * CDIM;
    const int r0 = tid >> 2, s0 = (tid & 3) * 8;

#define STAGE_R(kk, bsel) do {                                                  \
    const int dt_ = (kk) >> 3, ci0_ = ((kk) & 7) * 32, k0_ = (kk) * 32;         \
    gld16(wA + (size_t)r0 * 768 + k0_ + s0,        &As[bsel][tid * 8]);         \
    gld16(wA + (size_t)(r0 + 64) * 768 + k0_ + s0, &As[bsel][tid * 8 + 2048]);  \
    gld16(cB + (size_t)(r0 + dt_) * 256 + ci0_ + s0,      &Bs[bsel][tid * 8]);  \
    gld16(cB + (size_t)(r0 + 64 + dt_) * 256 + ci0_ + s0, &Bs[bsel][tid * 8 + 2048]); \
} while (0)

    STAGE_R(0, 0);

    f32x4 acc[4][4];
#pragma unroll
    for (int mt = 0; mt < 4; ++mt) {
        const int cb = m0 + (wv & 1) * 64 + mt * 16 + quad * 4;
        const float4 b4 = *(const float4*)(bo + cb);
#pragma unroll
        for (int nt = 0; nt < 4; ++nt) acc[mt][nt] = (f32x4){b4.x, b4.y, b4.z, b4.w};
    }

    int bsel = 0;
    for (int kk = 0; kk < 24; ++kk) {
        __syncthreads();
        if (kk < 23) STAGE_R(kk + 1, bsel ^ 1);
        const short* Ab = &As[bsel][((wv & 1) * 64 + col) * 32 + quad * 8];
        const short* Bb = &Bs[bsel][((wv >> 1) * 64 + col) * 32 + quad * 8];
        bf16x8 af[4], bfr[4];
#pragma unroll
        for (int i = 0; i < 4; ++i) {
            af[i]  = *(const bf16x8*)(Ab + i * 512);
            bfr[i] = *(const bf16x8*)(Bb + i * 512);
        }
#pragma unroll
        for (int mt = 0; mt < 4; ++mt)
#pragma unroll
            for (int nt = 0; nt < 4; ++nt)
                acc[mt][nt] = __builtin_amdgcn_mfma_f32_16x16x32_bf16(af[mt], bfr[nt], acc[mt][nt], 0, 0, 0);
        bsel ^= 1;
    }

#pragma unroll
    for (int mt = 0; mt < 4; ++mt) {
        const int co = m0 + (wv & 1) * 64 + mt * 16 + quad * 4;
#pragma unroll
        for (int nt = 0; nt < 4; ++nt) {
            const int t = t0 + (wv >> 1) * 64 + nt * 16 + col;
            const size_t o = ((size_t)b * TDIM + t) * CDIM + co;
            const float4 xv = *(const float4*)(x + o);
            const f32x4 a = acc[mt][nt];
            *(float4*)(out + o) = make_float4(a[0] + xv.x, a[1] + xv.y, a[2] + xv.z, a[3] + xv.w);
        }
    }
#undef STAGE_R
}

// ---------------------------------------------------------------------------
// MFMA flash attention, R8: OCCUPANCY DOUBLING. Memory structure = R1/R7's
// battle-tested scheme (reg-staged ds_write + one barrier, KVBLK=64,
// swizzled LDS, verified conflict-free & deterministic).
//
// R7 post-mortem: register reorder null -> scheduler already extracts intra-
// wave ILP. Surviving facts: MfmaUtil 33 / VALUBusy 46 / Occupancy 27% with
// grid 1024 = exactly 4 blocks/CU = 4 waves/SIMD. Each wave's kt-body is a
// serial chain (QK -> 32 exp on trans pipe -> pack -> PV); 4 chains/SIMD,
// re-aligned by the per-kt barrier, cannot cover chain latency -> dual-idle.
// VGPR 44 and LDS 16KB both allow 8 blocks/CU; only the grid prevents it.
//
// R8: halve per-block q-tile (each wave owns 16 q-rows, one MFMA tile);
// grid (64 bh, 32 qtiles) = 2048 blocks = 8 blocks/CU = 8 waves/SIMD.
// Same total MFMA/exp work; staging doubles but is L2-absorbed (~13 TB/s
// vs 34.5 ceiling; HBM FETCH unchanged). __launch_bounds__(256,8) caps
// VGPR at 64 (expect ~36-40).
// S^T trick (A=K, B=Q); l via ones-A-frag MFMA; raw v_exp_f32 (q pre-scaled
// by log2e/sqrt(D)). Grid (bh, qtile): bh fixes the XCD, K/V L2-resident.
// ---------------------------------------------------------------------------
__global__ __launch_bounds__(256, 8) void attn_kernel(
    const short* __restrict__ q, const short* __restrict__ k,
    const short* __restrict__ vt2, short* __restrict__ cp)
{
    __shared__ short ks[2][2048];
    __shared__ short vs[2][2048];
    const int tid = threadIdx.x;
    const int wv = tid >> 6, lane = tid & 63, quad = lane >> 4, col = lane & 15;
    const int bh = blockIdx.x;                    // XCD-locality: bh fixes XCD
    const int q0 = blockIdx.y * 64 + wv * 16;     // 16 q-rows per wave

    const short* qb = q + (size_t)bh * TDIM * DDIM;
    const short* kb = k + (size_t)bh * TDIM * DDIM;
    const short* vb = vt2 + (size_t)bh * TDIM * DDIM;
    const int so = tid * 8;                       // global staging offset (shorts)
    // swizzled LDS staging offset: row=tid>>2, slot=(tid&3)^((tid>>3)&3)
    const int sw = (tid >> 2) * 32 + (((tid & 3) ^ ((tid >> 3) & 3)) << 3);

    // stage tile 0 (regs -> LDS, swizzled)
    {
        uint4 kr = *(const uint4*)(kb + so);
        uint4 vr = *(const uint4*)(vb + so);
        *(uint4*)&ks[0][sw] = kr;
        *(uint4*)&vs[0][sw] = vr;
    }

    bf16x8 qf = *(const bf16x8*)(qb + (size_t)(q0 + col) * DDIM + quad * 8);

    f32x4 acc0 = {0.f,0.f,0.f,0.f};   // output d = quad*4 + r      (0..15)
    f32x4 acc1 = {0.f,0.f,0.f,0.f};   // output d = 16 + quad*4 + r (16..31)
    f32x4 accl = {0.f,0.f,0.f,0.f};   // ones-row: l in every reg
    const f32x4 zero = {0.f, 0.f, 0.f, 0.f};
    const short one_bf = (short)0x3F80;   // bf16 1.0
    const bf16x8 ones = {one_bf, one_bf, one_bf, one_bf, one_bf, one_bf, one_bf, one_bf};

    // swizzled frag offset within tile: row=g*16+col, slot'=quad^((col>>1)&3)
    const int foff = col * 32 + ((quad ^ ((col >> 1) & 3)) << 3);

    union Pu { unsigned u[4]; bf16x8 v; };

#define MFMA(a_, b_, c_) __builtin_amdgcn_mfma_f32_16x16x32_bf16(a_, b_, c_, 0, 0, 0)

    __syncthreads();                              // tile 0 visible

    for (int kt = 0; kt < TDIM / 64; ++kt) {
        const int cur = kt & 1;
        // issue next tile's global loads FIRST (hidden under compute below)
        uint4 krn, vrn;
        const bool more = kt < TDIM / 64 - 1;
        if (more) {
            krn = *(const uint4*)(kb + (kt + 1) * 2048 + so);
            vrn = *(const uint4*)(vb + (kt + 1) * 2048 + so);
        }
        const short* kbase = &ks[cur][foff];
        const short* vbase = &vs[cur][foff];
        bf16x8 k0 = *(const bf16x8*)(kbase +    0), k1 = *(const bf16x8*)(kbase +  512);
        bf16x8 k2 = *(const bf16x8*)(kbase + 1024), k3 = *(const bf16x8*)(kbase + 1536);
        bf16x8 v0 = *(const bf16x8*)(vbase +    0), v1 = *(const bf16x8*)(vbase +  512);
        bf16x8 v2 = *(const bf16x8*)(vbase + 1024), v3 = *(const bf16x8*)(vbase + 1536);
        // QK^T for the wave's 16 q-rows over 64 keys
        f32x4 s0 = MFMA(k0, qf, zero), s1 = MFMA(k1, qf, zero);
        f32x4 s2 = MFMA(k2, qf, zero), s3 = MFMA(k3, qf, zero);
        // exp + pack
        float e0 = EXP2(s0[0]), e1 = EXP2(s0[1]), e2 = EXP2(s0[2]), e3 = EXP2(s0[3]);
        float e4 = EXP2(s1[0]), e5 = EXP2(s1[1]), e6 = EXP2(s1[2]), e7 = EXP2(s1[3]);
        float e8 = EXP2(s2[0]), e9 = EXP2(s2[1]), eA = EXP2(s2[2]), eB = EXP2(s2[3]);
        float eC = EXP2(s3[0]), eD = EXP2(s3[1]), eE = EXP2(s3[2]), eF = EXP2(s3[3]);
        Pu P0, P1;
        P0.u[0] = pk2t(e0, e1); P0.u[1] = pk2t(e2, e3);
        P0.u[2] = pk2t(e4, e5); P0.u[3] = pk2t(e6, e7);
        P1.u[0] = pk2t(e8, e9); P1.u[1] = pk2t(eA, eB);
        P1.u[2] = pk2t(eC, eD); P1.u[3] = pk2t(eE, eF);
        // PV + l
        acc0 = MFMA(v0, P0.v, acc0);  acc1 = MFMA(v1, P0.v, acc1);
        accl = MFMA(ones, P0.v, accl);
        acc0 = MFMA(v2, P1.v, acc0);  acc1 = MFMA(v3, P1.v, acc1);
        accl = MFMA(ones, P1.v, accl);
        // ds_write staged tile kt+1 (buffer cur^1: its readers sealed by the
        // barrier at end of iteration kt-1)
        if (more) {
            *(uint4*)&ks[cur ^ 1][sw] = krn;
            *(uint4*)&vs[cur ^ 1][sw] = vrn;
        }
        __syncthreads();   // seals: my tile-(kt+1) writes visible; all reads of cur done
    }

    const int b = bh >> 3, hh = bh & 7;
    {
        const float inv = 1.f / accl[0];   // full-key sum, identical in all regs
        const int t = q0 + col;
        short* crow = cp + ((size_t)b * TP + t + 1) * CDIM + hh * DDIM;
        uint2 u0 = make_uint2(pk2(acc0[0] * inv, acc0[1] * inv),
                              pk2(acc0[2] * inv, acc0[3] * inv));
        uint2 u1 = make_uint2(pk2(acc1[0] * inv, acc1[1] * inv),
                              pk2(acc1[2] * inv, acc1[3] * inv));
        *(uint2*)(crow + quad * 4)      = u0;
        *(uint2*)(crow + 16 + quad * 4) = u1;
    }
#undef MFMA
}

// ---------------------------------------------------------------------------
extern "C" void kernel_launch(void* const* d_in, const int* in_sizes, int n_in,
                              void* d_out, int out_size, void* d_ws, size_t ws_size,
                              hipStream_t stream) {
    const float* x  = (const float*)d_in[0];
    const float* Wq = (const float*)d_in[1];
    const float* bq = (const float*)d_in[2];
    const float* Wk = (const float*)d_in[3];
    const float* bk = (const float*)d_in[4];
    const float* Wv = (const float*)d_in[5];
    const float* bv = (const float*)d_in[6];
    const float* Wo = (const float*)d_in[7];
    const float* bo = (const float*)d_in[8];
    float* out = (float*)d_out;

    short* p = (short*)d_ws;
    short* xbfp = p; p += (size_t)BDIM * TP * CDIM;        // 4,198,400
    short* cpb  = p; p += (size_t)BDIM * TP * CDIM;        // 4,198,400
    short* qbuf = p; p += (size_t)BDIM * HDIM * TDIM * DDIM; // 4,194,304
    short* kbuf = p; p += (size_t)BDIM * HDIM * TDIM * DDIM;
    short* vt2  = p; p += (size_t)BDIM * HDIM * TDIM * DDIM;
    short* wcat = p; p += 768 * 768;
    short* wot  = p; p += 256 * 768;
    // total ~43.5 MB

    prep_kernel<<<dim3(XBLK + WBLK), 256, 0, stream>>>(x, Wq, Wk, Wv, Wo, xbfp, cpb, wcat, wot);
    gemm_qkv<<<dim3(128, 6), 256, 0, stream>>>(xbfp, wcat, bq, bk, bv, qbuf, kbuf, vt2);
    attn_kernel<<<dim3(64, 32), 256, 0, stream>>>(qbuf, kbuf, vt2, cpb);
    gemm_res<<<dim3(128, 2), 256, 0, stream>>>(cpb, wot, bo, x, out);
}

// Round 11
// 176.057 us; speedup vs baseline: 1.0718x; 1.0718x over previous
//
#include <hip/hip_runtime.h>
#include <math.h>

// Problem constants (fixed by reference)
#define BDIM 8
#define TDIM 2048
#define CDIM 256
#define HDIM 8
#define DDIM 32
#define TP   (TDIM + 2)   // padded time (halo row above and below, zeroed)

typedef __attribute__((ext_vector_type(8))) short bf16x8;   // MFMA A/B frag (4 VGPR)
typedef __attribute__((ext_vector_type(4))) float f32x4;    // MFMA C/D frag

#if __has_builtin(__builtin_amdgcn_exp2f)
#define EXP2(x) __builtin_amdgcn_exp2f(x)
#else
#define EXP2(x) exp2f(x)
#endif

// pack two f32 -> one dword of two bf16 (round-half-up: +0x8000 then v_perm)
__device__ __forceinline__ unsigned pk2(float lo, float hi) {
    union { float f; unsigned u; } a, b;
    a.f = lo; b.f = hi;
    return __builtin_amdgcn_perm(b.u + 0x8000u, a.u + 0x8000u, 0x07060302u);
}
// truncating pack (1 op). For p >= 0 the <=0.8% downward bias cancels between
// softmax numerator and denominator (l is summed from the SAME bf16 values).
__device__ __forceinline__ unsigned pk2t(float lo, float hi) {
    union { float f; unsigned u; } a, b;
    a.f = lo; b.f = hi;
    return __builtin_amdgcn_perm(b.u, a.u, 0x07060302u);
}
__device__ __forceinline__ short bf1(float v) {
    union { float f; unsigned u; } a; a.f = v;
    return (short)((a.u + 0x8000u) >> 16);
}
// async global->LDS, 16B per lane (dest must be wave-uniform base + lane*16)
__device__ __forceinline__ void gld16(const short* g, short* l) {
    __builtin_amdgcn_global_load_lds((const __attribute__((address_space(1))) void*)g,
                                     (__attribute__((address_space(3))) void*)l, 16, 0, 0);
}

#define XBLK 832   // prep: blocks doing x-convert + halos
#define WBLK 192   // prep: blocks doing LDS-tiled weight transpose (12 pairs x 16)

// ---------------------------------------------------------------------------
// Prep: x -> bf16 padded xbfp[B][TP][C] (halos zero); weights -> bf16 W^T
// (row=co, col=k=dt*256+ci) via LDS-tiled transpose (coalesced both sides).
// ---------------------------------------------------------------------------
__global__ __launch_bounds__(256) void prep_kernel(
    const float* __restrict__ x,
    const float* __restrict__ Wq, const float* __restrict__ Wk,
    const float* __restrict__ Wv, const float* __restrict__ Wo,
    short* __restrict__ xbfp, short* __restrict__ cp,
    short* __restrict__ wcat, short* __restrict__ wot)
{
    const int tid = threadIdx.x;
    if (blockIdx.x < XBLK) {
        const int NX = BDIM * TDIM * 64;    // float4 chunks of x
        const int NH = 4096;                // halo dwords (xbfp + cp)
        unsigned* xw = (unsigned*)xbfp;
        unsigned* cw = (unsigned*)cp;
        for (int i = blockIdx.x * 256 + tid; i < NX + NH; i += XBLK * 256) {
            if (i < NX) {
                const int bt = i >> 6, c4 = i & 63;
                const int b = bt >> 11, t = bt & 2047;
                const float4 f = *(const float4*)(x + (size_t)bt * 256 + c4 * 4);
                const size_t wo_ = (size_t)(b * TP + t + 1) * 128 + c4 * 2;
                xw[wo_]     = pk2(f.x, f.y);
                xw[wo_ + 1] = pk2(f.z, f.w);
            } else {
                const int hz = i - NX;
                const int half = hz >> 11, z = hz & 2047;
                const int b = z >> 8, r = (z >> 7) & 1, wofs = z & 127;
                const size_t w_ = ((size_t)b * TP + (size_t)r * (TP - 1)) * 128 + wofs;
                if (half == 0) xw[w_] = 0u; else cw[w_] = 0u;
            }
        }
    } else {
        // weight transpose: 12 (dt,mat) pairs x 16 subtiles of 64ci x 64co
        __shared__ float xs[64][65];
        const int wb = blockIdx.x - XBLK;
        const int pair = wb >> 4, sub = wb & 15;
        const int dt = pair >> 2, mat = pair & 3;        // mat: 0=q 1=k 2=v 3=o
        const int ci0 = (sub >> 2) * 64, co0 = (sub & 3) * 64;
        const float* W = mat == 0 ? Wq : mat == 1 ? Wk : mat == 2 ? Wv : Wo;
        const float* src = W + dt * 65536 + (size_t)ci0 * 256 + co0;
        for (int idx = tid; idx < 4096; idx += 256) {
            const int r = idx >> 6, c = idx & 63;
            xs[r][c] = src[(size_t)r * 256 + c];
        }
        __syncthreads();
        short* dstbase = (mat < 3) ? (wcat + (size_t)(mat * 256 + co0) * 768)
                                   : (wot + (size_t)co0 * 768);
        for (int idx = tid; idx < 512; idx += 256) {
            const int co_l = idx >> 3, ci_l = (idx & 7) * 8;
            uint4 u;
            u.x = pk2(xs[ci_l + 0][co_l], xs[ci_l + 1][co_l]);
            u.y = pk2(xs[ci_l + 2][co_l], xs[ci_l + 3][co_l]);
            u.z = pk2(xs[ci_l + 4][co_l], xs[ci_l + 5][co_l]);
            u.w = pk2(xs[ci_l + 6][co_l], xs[ci_l + 7][co_l]);
            *(uint4*)(dstbase + (size_t)co_l * 768 + dt * 256 + ci0 + ci_l) = u;
        }
    }
}

// ---------------------------------------------------------------------------
// QKV conv as double-buffered MFMA GEMM (m97 structure).
// Result transposed: A = W rows (m=co_cat), B = x rows (n=t).
// Block 256 thr = 4 waves; tile 128 co x 128 t; BK=32 (k = dt*256+ci, chunks
// never straddle dt). grid (128 t-tiles, 6 co-tiles); blockIdx.y>>1 = q/k/v.
// ---------------------------------------------------------------------------
__global__ __launch_bounds__(256) void gemm_qkv(
    const short* __restrict__ xbfp, const short* __restrict__ wcat,
    const float* __restrict__ bq, const float* __restrict__ bk,
    const float* __restrict__ bv,
    short* __restrict__ qo, short* __restrict__ ko, short* __restrict__ vt2)
{
    __shared__ short As[2][4096];
    __shared__ short Bs[2][4096];
    const int tid = threadIdx.x;
    const int wv = tid >> 6, lane = tid & 63, quad = lane >> 4, col = lane & 15;
    const int bx = blockIdx.x;
    const int b = bx >> 4, t0 = (bx & 15) * 128;
    const int by = blockIdx.y;
    const int qkv = by >> 1;
    const int m0 = by * 128;

    const short* wA = wcat + (size_t)m0 * 768;
    const short* xB = xbfp + ((size_t)b * TP + t0) * CDIM;
    const int r0 = tid >> 2, s0 = (tid & 3) * 8;   // chunk row / in-row offset

#define STAGE_Q(kk, bsel) do {                                                  \
    const int dt_ = (kk) >> 3, ci0_ = ((kk) & 7) * 32, k0_ = (kk) * 32;         \
    gld16(wA + (size_t)r0 * 768 + k0_ + s0,        &As[bsel][tid * 8]);         \
    gld16(wA + (size_t)(r0 + 64) * 768 + k0_ + s0, &As[bsel][tid * 8 + 2048]);  \
    gld16(xB + (size_t)(r0 + dt_) * 256 + ci0_ + s0,      &Bs[bsel][tid * 8]);  \
    gld16(xB + (size_t)(r0 + 64 + dt_) * 256 + ci0_ + s0, &Bs[bsel][tid * 8 + 2048]); \
} while (0)

    STAGE_Q(0, 0);

    const float* bias = qkv == 0 ? bq : qkv == 1 ? bk : bv;
    f32x4 acc[4][4];
#pragma unroll
    for (int mt = 0; mt < 4; ++mt) {
        const int cb = ((m0 + (wv & 1) * 64 + mt * 16) & 255) + quad * 4;
        const float4 b4 = *(const float4*)(bias + cb);
#pragma unroll
        for (int nt = 0; nt < 4; ++nt) acc[mt][nt] = (f32x4){b4.x, b4.y, b4.z, b4.w};
    }

    int bsel = 0;
    for (int kk = 0; kk < 24; ++kk) {
        __syncthreads();
        if (kk < 23) STAGE_Q(kk + 1, bsel ^ 1);
        const short* Ab = &As[bsel][((wv & 1) * 64 + col) * 32 + quad * 8];
        const short* Bb = &Bs[bsel][((wv >> 1) * 64 + col) * 32 + quad * 8];
        bf16x8 af[4], bfr[4];
#pragma unroll
        for (int i = 0; i < 4; ++i) {
            af[i]  = *(const bf16x8*)(Ab + i * 512);
            bfr[i] = *(const bf16x8*)(Bb + i * 512);
        }
#pragma unroll
        for (int mt = 0; mt < 4; ++mt)
#pragma unroll
            for (int nt = 0; nt < 4; ++nt)
                acc[mt][nt] = __builtin_amdgcn_mfma_f32_16x16x32_bf16(af[mt], bfr[nt], acc[mt][nt], 0, 0, 0);
        bsel ^= 1;
    }

    const float qs = 0.25503000508221157f;   // log2(e)/sqrt(32)
#pragma unroll
    for (int mt = 0; mt < 4; ++mt) {
        const int cocat = m0 + (wv & 1) * 64 + mt * 16 + quad * 4;
        const int co = cocat & 255;
        const int hh = co >> 5, d = co & 31;
        const size_t bh = (size_t)b * HDIM + hh;
#pragma unroll
        for (int nt = 0; nt < 4; ++nt) {
            const int t = t0 + (wv >> 1) * 64 + nt * 16 + col;
            const f32x4 a = acc[mt][nt];
            if (qkv == 0) {
                uint2 u = make_uint2(pk2(a[0] * qs, a[1] * qs), pk2(a[2] * qs, a[3] * qs));
                *(uint2*)(qo + (bh * TDIM + t) * DDIM + d) = u;
            } else if (qkv == 1) {
                uint2 u = make_uint2(pk2(a[0], a[1]), pk2(a[2], a[3]));
                *(uint2*)(ko + (bh * TDIM + t) * DDIM + d) = u;
            } else {
                const int kt = t >> 6, u6 = t & 63, kg = u6 >> 5, rr = u6 & 31;
                const int j = ((rr >> 4) << 2) | (rr & 3), qd = (rr >> 2) & 3;
                short* vb2 = vt2 + ((bh * 32 + kt) * 2 + kg) * 1024 + qd * 8 + j;
#pragma unroll
                for (int r = 0; r < 4; ++r) vb2[(d + r) * 32] = bf1(a[r]);
            }
        }
    }
#undef STAGE_Q
}

// ---------------------------------------------------------------------------
// Output conv + residual. R9: tile 64t x 128co (was 128x128) -> grid (256,2)
// = 512 blocks = 2 blocks/CU (was 1). Mechanism: at 1 block/CU every
// stage->barrier iteration exposed full vmcnt/L2 drain with zero co-resident
// waves to cover it (m233 stall, no TLP rescue). 2 blocks/CU lets one block
// compute while the other drains. LDS 24KB (A 128x32 + B 64x32, dbuf).
// Same verified GEMM template, parameter change only.
// ---------------------------------------------------------------------------
__global__ __launch_bounds__(256) void gemm_res(
    const short* __restrict__ cp, const short* __restrict__ wot,
    const float* __restrict__ bo, const float* __restrict__ x,
    float* __restrict__ out)
{
    __shared__ short As[2][4096];
    __shared__ short Bs[2][2048];
    const int tid = threadIdx.x;
    const int wv = tid >> 6, lane = tid & 63, quad = lane >> 4, col = lane & 15;
    const int bx = blockIdx.x;
    const int b = bx >> 5, t0 = (bx & 31) * 64;
    const int m0 = blockIdx.y * 128;

    const short* wA = wot + (size_t)m0 * 768;
    const short* cB = cp + ((size_t)b * TP + t0) * CDIM;
    const int r0 = tid >> 2, s0 = (tid & 3) * 8;

#define STAGE_R(kk, bsel) do {                                                  \
    const int dt_ = (kk) >> 3, ci0_ = ((kk) & 7) * 32, k0_ = (kk) * 32;         \
    gld16(wA + (size_t)r0 * 768 + k0_ + s0,        &As[bsel][tid * 8]);         \
    gld16(wA + (size_t)(r0 + 64) * 768 + k0_ + s0, &As[bsel][tid * 8 + 2048]);  \
    gld16(cB + (size_t)(r0 + dt_) * 256 + ci0_ + s0,      &Bs[bsel][tid * 8]);  \
} while (0)

    STAGE_R(0, 0);

    f32x4 acc[4][2];
#pragma unroll
    for (int mt = 0; mt < 4; ++mt) {
        const int cb = m0 + (wv & 1) * 64 + mt * 16 + quad * 4;
        const float4 b4 = *(const float4*)(bo + cb);
#pragma unroll
        for (int nt = 0; nt < 2; ++nt) acc[mt][nt] = (f32x4){b4.x, b4.y, b4.z, b4.w};
    }

    int bsel = 0;
    for (int kk = 0; kk < 24; ++kk) {
        __syncthreads();
        if (kk < 23) STAGE_R(kk + 1, bsel ^ 1);
        const short* Ab = &As[bsel][((wv & 1) * 64 + col) * 32 + quad * 8];
        const short* Bb = &Bs[bsel][((wv >> 1) * 32 + col) * 32 + quad * 8];
        bf16x8 af[4], bfr[2];
#pragma unroll
        for (int i = 0; i < 4; ++i) af[i]  = *(const bf16x8*)(Ab + i * 512);
#pragma unroll
        for (int i = 0; i < 2; ++i) bfr[i] = *(const bf16x8*)(Bb + i * 512);
#pragma unroll
        for (int mt = 0; mt < 4; ++mt)
#pragma unroll
            for (int nt = 0; nt < 2; ++nt)
                acc[mt][nt] = __builtin_amdgcn_mfma_f32_16x16x32_bf16(af[mt], bfr[nt], acc[mt][nt], 0, 0, 0);
        bsel ^= 1;
    }

#pragma unroll
    for (int mt = 0; mt < 4; ++mt) {
        const int co = m0 + (wv & 1) * 64 + mt * 16 + quad * 4;
#pragma unroll
        for (int nt = 0; nt < 2; ++nt) {
            const int t = t0 + (wv >> 1) * 32 + nt * 16 + col;
            const size_t o = ((size_t)b * TDIM + t) * CDIM + co;
            const float4 xv = *(const float4*)(x + o);
            const f32x4 a = acc[mt][nt];
            *(float4*)(out + o) = make_float4(a[0] + xv.x, a[1] + xv.y, a[2] + xv.z, a[3] + xv.w);
        }
    }
#undef STAGE_R
}

// ---------------------------------------------------------------------------
// MFMA flash attention — R7-exact (verified deterministic, 49.0us).
// Reg-staged ds_write + one barrier per 64-key tile, swizzled LDS
// (conflict-free, verified 0), pipelined QK(q0)+QK(q1) -> exp(A) -> PV(A) ->
// exp(B) -> PV(B). No setprio. S^T trick (A=K, B=Q); l via ones-A-frag MFMA;
// raw v_exp_f32 (q pre-scaled by log2e/sqrt(D)).
// Five structural variants (R1/R5/R7/R8 + reorder) all land 49-54us with
// invariant VALU~23us / MFMA~16us: consistent with the ~27us trans-pipe
// floor of 268M v_exp_f32 at quarter rate. Declared local floor.
// ---------------------------------------------------------------------------
__global__ __launch_bounds__(256, 4) void attn_kernel(
    const short* __restrict__ q, const short* __restrict__ k,
    const short* __restrict__ vt2, short* __restrict__ cp)
{
    __shared__ short ks[2][2048];
    __shared__ short vs[2][2048];
    const int tid = threadIdx.x;
    const int wv = tid >> 6, lane = tid & 63, quad = lane >> 4, col = lane & 15;
    const int bh = blockIdx.x;                    // XCD-locality: bh fixes XCD
    const int q0 = blockIdx.y * 128 + wv * 32;

    const short* qb = q + (size_t)bh * TDIM * DDIM;
    const short* kb = k + (size_t)bh * TDIM * DDIM;
    const short* vb = vt2 + (size_t)bh * TDIM * DDIM;
    const int so = tid * 8;                       // global staging offset (shorts)
    // swizzled LDS staging offset: row=tid>>2, slot=(tid&3)^((tid>>3)&3)
    const int sw = (tid >> 2) * 32 + (((tid & 3) ^ ((tid >> 3) & 3)) << 3);

    // stage tile 0 (regs -> LDS, swizzled)
    {
        uint4 kr = *(const uint4*)(kb + so);
        uint4 vr = *(const uint4*)(vb + so);
        *(uint4*)&ks[0][sw] = kr;
        *(uint4*)&vs[0][sw] = vr;
    }

    bf16x8 qf0 = *(const bf16x8*)(qb + (size_t)(q0 + col) * DDIM + quad * 8);
    bf16x8 qf1 = *(const bf16x8*)(qb + (size_t)(q0 + 16 + col) * DDIM + quad * 8);

    f32x4 acc0_0 = {0.f,0.f,0.f,0.f}, acc0_1 = {0.f,0.f,0.f,0.f};
    f32x4 acc1_0 = {0.f,0.f,0.f,0.f}, acc1_1 = {0.f,0.f,0.f,0.f};
    f32x4 accl_0 = {0.f,0.f,0.f,0.f}, accl_1 = {0.f,0.f,0.f,0.f};
    const f32x4 zero = {0.f, 0.f, 0.f, 0.f};
    const short one_bf = (short)0x3F80;   // bf16 1.0
    const bf16x8 ones = {one_bf, one_bf, one_bf, one_bf, one_bf, one_bf, one_bf, one_bf};

    // swizzled frag offset within tile: row=g*16+col, slot'=quad^((col>>1)&3)
    const int foff = col * 32 + ((quad ^ ((col >> 1) & 3)) << 3);

    union Pu { unsigned u[4]; bf16x8 v; };

#define MFMA(a_, b_, c_) __builtin_amdgcn_mfma_f32_16x16x32_bf16(a_, b_, c_, 0, 0, 0)

// exp+pack 16 f32 (4 frags) -> two bf16x8 B-operands
#define EXPPACK(s0_, s1_, s2_, s3_, PP0, PP1) do {                         \
    float e0 = EXP2(s0_[0]), e1 = EXP2(s0_[1]), e2 = EXP2(s0_[2]), e3 = EXP2(s0_[3]); \
    float e4 = EXP2(s1_[0]), e5 = EXP2(s1_[1]), e6 = EXP2(s1_[2]), e7 = EXP2(s1_[3]); \
    float e8 = EXP2(s2_[0]), e9 = EXP2(s2_[1]), eA = EXP2(s2_[2]), eB = EXP2(s2_[3]); \
    float eC = EXP2(s3_[0]), eD = EXP2(s3_[1]), eE = EXP2(s3_[2]), eF = EXP2(s3_[3]); \
    PP0.u[0] = pk2t(e0, e1); PP0.u[1] = pk2t(e2, e3);                      \
    PP0.u[2] = pk2t(e4, e5); PP0.u[3] = pk2t(e6, e7);                      \
    PP1.u[0] = pk2t(e8, e9); PP1.u[1] = pk2t(eA, eB);                      \
    PP1.u[2] = pk2t(eC, eD); PP1.u[3] = pk2t(eE, eF);                      \
} while (0)

// 6-MFMA PV step into one q-slot's accumulators
#define PVSTEP(A0, A1, AL, PP0, PP1) do {                                  \
    A0 = MFMA(v0, PP0.v, A0);  A1 = MFMA(v1, PP0.v, A1);                   \
    AL = MFMA(ones, PP0.v, AL);                                            \
    A0 = MFMA(v2, PP1.v, A0);  A1 = MFMA(v3, PP1.v, A1);                   \
    AL = MFMA(ones, PP1.v, AL);                                            \
} while (0)

    __syncthreads();                              // tile 0 visible

    for (int kt = 0; kt < TDIM / 64; ++kt) {
        const int cur = kt & 1;
        // issue next tile's global loads FIRST (hidden under compute below)
        uint4 krn, vrn;
        const bool more = kt < TDIM / 64 - 1;
        if (more) {
            krn = *(const uint4*)(kb + (kt + 1) * 2048 + so);
            vrn = *(const uint4*)(vb + (kt + 1) * 2048 + so);
        }
        const short* kbase = &ks[cur][foff];
        const short* vbase = &vs[cur][foff];
        bf16x8 k0 = *(const bf16x8*)(kbase +    0), k1 = *(const bf16x8*)(kbase +  512);
        bf16x8 k2 = *(const bf16x8*)(kbase + 1024), k3 = *(const bf16x8*)(kbase + 1536);
        bf16x8 v0 = *(const bf16x8*)(vbase +    0), v1 = *(const bf16x8*)(vbase +  512);
        bf16x8 v2 = *(const bf16x8*)(vbase + 1024), v3 = *(const bf16x8*)(vbase + 1536);
        // QK for BOTH q-slots back-to-back: 8 independent MFMAs fill the pipe
        f32x4 sA0 = MFMA(k0, qf0, zero), sA1 = MFMA(k1, qf0, zero);
        f32x4 sA2 = MFMA(k2, qf0, zero), sA3 = MFMA(k3, qf0, zero);
        f32x4 sB0 = MFMA(k0, qf1, zero), sB1 = MFMA(k1, qf1, zero);
        f32x4 sB2 = MFMA(k2, qf1, zero), sB3 = MFMA(k3, qf1, zero);
        // exp/pack(A) on VALU while QK(B) drains on matrix pipe
        Pu PA0, PA1;
        EXPPACK(sA0, sA1, sA2, sA3, PA0, PA1);
        // PV(A) on matrix pipe while exp/pack(B) runs on VALU
        PVSTEP(acc0_0, acc1_0, accl_0, PA0, PA1);
        Pu PB0, PB1;
        EXPPACK(sB0, sB1, sB2, sB3, PB0, PB1);
        PVSTEP(acc0_1, acc1_1, accl_1, PB0, PB1);
        // ds_write staged tile kt+1 (buffer cur^1: its readers sealed by the
        // barrier at end of iteration kt-1)
        if (more) {
            *(uint4*)&ks[cur ^ 1][sw] = krn;
            *(uint4*)&vs[cur ^ 1][sw] = vrn;
        }
        __syncthreads();   // seals: my tile-(kt+1) writes visible; all reads of cur done
    }

    const int b = bh >> 3, hh = bh & 7;
    {
        const float inv = 1.f / accl_0[0];   // full-key sum, identical in all regs
        const int t = q0 + col;
        short* crow = cp + ((size_t)b * TP + t + 1) * CDIM + hh * DDIM;
        uint2 u0 = make_uint2(pk2(acc0_0[0] * inv, acc0_0[1] * inv),
                              pk2(acc0_0[2] * inv, acc0_0[3] * inv));
        uint2 u1 = make_uint2(pk2(acc1_0[0] * inv, acc1_0[1] * inv),
                              pk2(acc1_0[2] * inv, acc1_0[3] * inv));
        *(uint2*)(crow + quad * 4)      = u0;
        *(uint2*)(crow + 16 + quad * 4) = u1;
    }
    {
        const float inv = 1.f / accl_1[0];
        const int t = q0 + 16 + col;
        short* crow = cp + ((size_t)b * TP + t + 1) * CDIM + hh * DDIM;
        uint2 u0 = make_uint2(pk2(acc0_1[0] * inv, acc0_1[1] * inv),
                              pk2(acc0_1[2] * inv, acc0_1[3] * inv));
        uint2 u1 = make_uint2(pk2(acc1_1[0] * inv, acc1_1[1] * inv),
                              pk2(acc1_1[2] * inv, acc1_1[3] * inv));
        *(uint2*)(crow + quad * 4)      = u0;
        *(uint2*)(crow + 16 + quad * 4) = u1;
    }
#undef MFMA
#undef EXPPACK
#undef PVSTEP
}

// ---------------------------------------------------------------------------
extern "C" void kernel_launch(void* const* d_in, const int* in_sizes, int n_in,
                              void* d_out, int out_size, void* d_ws, size_t ws_size,
                              hipStream_t stream) {
    const float* x  = (const float*)d_in[0];
    const float* Wq = (const float*)d_in[1];
    const float* bq = (const float*)d_in[2];
    const float* Wk = (const float*)d_in[3];
    const float* bk = (const float*)d_in[4];
    const float* Wv = (const float*)d_in[5];
    const float* bv = (const float*)d_in[6];
    const float* Wo = (const float*)d_in[7];
    const float* bo = (const float*)d_in[8];
    float* out = (float*)d_out;

    short* p = (short*)d_ws;
    short* xbfp = p; p += (size_t)BDIM * TP * CDIM;        // 4,198,400
    short* cpb  = p; p += (size_t)BDIM * TP * CDIM;        // 4,198,400
    short* qbuf = p; p += (size_t)BDIM * HDIM * TDIM * DDIM; // 4,194,304
    short* kbuf = p; p += (size_t)BDIM * HDIM * TDIM * DDIM;
    short* vt2  = p; p += (size_t)BDIM * HDIM * TDIM * DDIM;
    short* wcat = p; p += 768 * 768;
    short* wot  = p; p += 256 * 768;
    // total ~43.5 MB

    prep_kernel<<<dim3(XBLK + WBLK), 256, 0, stream>>>(x, Wq, Wk, Wv, Wo, xbfp, cpb, wcat, wot);
    gemm_qkv<<<dim3(128, 6), 256, 0, stream>>>(xbfp, wcat, bq, bk, bv, qbuf, kbuf, vt2);
    attn_kernel<<<dim3(64, 16), 256, 0, stream>>>(qbuf, kbuf, vt2, cpb);
    gemm_res<<<dim3(256, 2), 256, 0, stream>>>(cpb, wot, bo, x, out);
}

// Round 14
// 175.796 us; speedup vs baseline: 1.0734x; 1.0015x over previous
//
#include <hip/hip_runtime.h>
#include <math.h>

// Problem constants (fixed by reference)
#define BDIM 8
#define TDIM 2048
#define CDIM 256
#define HDIM 8
#define DDIM 32
#define TP   (TDIM + 2)   // padded time (halo row above and below, zeroed)

typedef __attribute__((ext_vector_type(8))) short bf16x8;   // MFMA A/B frag (4 VGPR)
typedef __attribute__((ext_vector_type(4))) float f32x4;    // MFMA C/D frag

#if __has_builtin(__builtin_amdgcn_exp2f)
#define EXP2(x) __builtin_amdgcn_exp2f(x)
#else
#define EXP2(x) exp2f(x)
#endif

// pack two f32 -> one dword of two bf16 (round-half-up: +0x8000 then v_perm)
__device__ __forceinline__ unsigned pk2(float lo, float hi) {
    union { float f; unsigned u; } a, b;
    a.f = lo; b.f = hi;
    return __builtin_amdgcn_perm(b.u + 0x8000u, a.u + 0x8000u, 0x07060302u);
}
// truncating pack (1 op). For p >= 0 the <=0.8% downward bias cancels between
// softmax numerator and denominator (l is summed from the SAME bf16 values).
__device__ __forceinline__ unsigned pk2t(float lo, float hi) {
    union { float f; unsigned u; } a, b;
    a.f = lo; b.f = hi;
    return __builtin_amdgcn_perm(b.u, a.u, 0x07060302u);
}
__device__ __forceinline__ short bf1(float v) {
    union { float f; unsigned u; } a; a.f = v;
    return (short)((a.u + 0x8000u) >> 16);
}
// async global->LDS, 16B per lane (dest must be wave-uniform base + lane*16)
__device__ __forceinline__ void gld16(const short* g, short* l) {
    __builtin_amdgcn_global_load_lds((const __attribute__((address_space(1))) void*)g,
                                     (__attribute__((address_space(3))) void*)l, 16, 0, 0);
}

#define XBLK 832   // prep: blocks doing x-convert + halos
#define WBLK 192   // prep: blocks doing LDS-tiled weight transpose (12 pairs x 16)

// ---------------------------------------------------------------------------
// Prep: x -> bf16 padded xbfp[B][TP][C] (halos zero); weights -> bf16 W^T
// (row=co, col=k=dt*256+ci) via LDS-tiled transpose (coalesced both sides).
// ---------------------------------------------------------------------------
__global__ __launch_bounds__(256) void prep_kernel(
    const float* __restrict__ x,
    const float* __restrict__ Wq, const float* __restrict__ Wk,
    const float* __restrict__ Wv, const float* __restrict__ Wo,
    short* __restrict__ xbfp, short* __restrict__ cp,
    short* __restrict__ wcat, short* __restrict__ wot)
{
    const int tid = threadIdx.x;
    if (blockIdx.x < XBLK) {
        const int NX = BDIM * TDIM * 64;    // float4 chunks of x
        const int NH = 4096;                // halo dwords (xbfp + cp)
        unsigned* xw = (unsigned*)xbfp;
        unsigned* cw = (unsigned*)cp;
        for (int i = blockIdx.x * 256 + tid; i < NX + NH; i += XBLK * 256) {
            if (i < NX) {
                const int bt = i >> 6, c4 = i & 63;
                const int b = bt >> 11, t = bt & 2047;
                const float4 f = *(const float4*)(x + (size_t)bt * 256 + c4 * 4);
                const size_t wo_ = (size_t)(b * TP + t + 1) * 128 + c4 * 2;
                xw[wo_]     = pk2(f.x, f.y);
                xw[wo_ + 1] = pk2(f.z, f.w);
            } else {
                const int hz = i - NX;
                const int half = hz >> 11, z = hz & 2047;
                const int b = z >> 8, r = (z >> 7) & 1, wofs = z & 127;
                const size_t w_ = ((size_t)b * TP + (size_t)r * (TP - 1)) * 128 + wofs;
                if (half == 0) xw[w_] = 0u; else cw[w_] = 0u;
            }
        }
    } else {
        // weight transpose: 12 (dt,mat) pairs x 16 subtiles of 64ci x 64co
        __shared__ float xs[64][65];
        const int wb = blockIdx.x - XBLK;
        const int pair = wb >> 4, sub = wb & 15;
        const int dt = pair >> 2, mat = pair & 3;        // mat: 0=q 1=k 2=v 3=o
        const int ci0 = (sub >> 2) * 64, co0 = (sub & 3) * 64;
        const float* W = mat == 0 ? Wq : mat == 1 ? Wk : mat == 2 ? Wv : Wo;
        const float* src = W + dt * 65536 + (size_t)ci0 * 256 + co0;
        for (int idx = tid; idx < 4096; idx += 256) {
            const int r = idx >> 6, c = idx & 63;
            xs[r][c] = src[(size_t)r * 256 + c];
        }
        __syncthreads();
        short* dstbase = (mat < 3) ? (wcat + (size_t)(mat * 256 + co0) * 768)
                                   : (wot + (size_t)co0 * 768);
        for (int idx = tid; idx < 512; idx += 256) {
            const int co_l = idx >> 3, ci_l = (idx & 7) * 8;
            uint4 u;
            u.x = pk2(xs[ci_l + 0][co_l], xs[ci_l + 1][co_l]);
            u.y = pk2(xs[ci_l + 2][co_l], xs[ci_l + 3][co_l]);
            u.z = pk2(xs[ci_l + 4][co_l], xs[ci_l + 5][co_l]);
            u.w = pk2(xs[ci_l + 6][co_l], xs[ci_l + 7][co_l]);
            *(uint4*)(dstbase + (size_t)co_l * 768 + dt * 256 + ci0 + ci_l) = u;
        }
    }
}

// ---------------------------------------------------------------------------
// QKV conv as double-buffered MFMA GEMM (m97 structure).
// Result transposed: A = W rows (m=co_cat), B = x rows (n=t).
// Block 256 thr = 4 waves; tile 128 co x 128 t; BK=32 (k = dt*256+ci, chunks
// never straddle dt). grid (128 t-tiles, 6 co-tiles); blockIdx.y>>1 = q/k/v.
// R12: __launch_bounds__(256,4) caps VGPR at 128. Theory: acc[4][4] (64) +
// 8 frags (32) + addressing was >128 -> 8 waves/CU -> only 2 of the grid's
// 3 blocks/CU co-resident (occupancy cliff at the 128 boundary, m69
// quantization) + straggler round. Cap -> 16 waves/CU -> 3 blocks resident.
// ---------------------------------------------------------------------------
__global__ __launch_bounds__(256, 4) void gemm_qkv(
    const short* __restrict__ xbfp, const short* __restrict__ wcat,
    const float* __restrict__ bq, const float* __restrict__ bk,
    const float* __restrict__ bv,
    short* __restrict__ qo, short* __restrict__ ko, short* __restrict__ vt2)
{
    __shared__ short As[2][4096];
    __shared__ short Bs[2][4096];
    const int tid = threadIdx.x;
    const int wv = tid >> 6, lane = tid & 63, quad = lane >> 4, col = lane & 15;
    const int bx = blockIdx.x;
    const int b = bx >> 4, t0 = (bx & 15) * 128;
    const int by = blockIdx.y;
    const int qkv = by >> 1;
    const int m0 = by * 128;

    const short* wA = wcat + (size_t)m0 * 768;
    const short* xB = xbfp + ((size_t)b * TP + t0) * CDIM;
    const int r0 = tid >> 2, s0 = (tid & 3) * 8;   // chunk row / in-row offset

#define STAGE_Q(kk, bsel) do {                                                  \
    const int dt_ = (kk) >> 3, ci0_ = ((kk) & 7) * 32, k0_ = (kk) * 32;         \
    gld16(wA + (size_t)r0 * 768 + k0_ + s0,        &As[bsel][tid * 8]);         \
    gld16(wA + (size_t)(r0 + 64) * 768 + k0_ + s0, &As[bsel][tid * 8 + 2048]);  \
    gld16(xB + (size_t)(r0 + dt_) * 256 + ci0_ + s0,      &Bs[bsel][tid * 8]);  \
    gld16(xB + (size_t)(r0 + 64 + dt_) * 256 + ci0_ + s0, &Bs[bsel][tid * 8 + 2048]); \
} while (0)

    STAGE_Q(0, 0);

    const float* bias = qkv == 0 ? bq : qkv == 1 ? bk : bv;
    f32x4 acc[4][4];
#pragma unroll
    for (int mt = 0; mt < 4; ++mt) {
        const int cb = ((m0 + (wv & 1) * 64 + mt * 16) & 255) + quad * 4;
        const float4 b4 = *(const float4*)(bias + cb);
#pragma unroll
        for (int nt = 0; nt < 4; ++nt) acc[mt][nt] = (f32x4){b4.x, b4.y, b4.z, b4.w};
    }

    int bsel = 0;
    for (int kk = 0; kk < 24; ++kk) {
        __syncthreads();
        if (kk < 23) STAGE_Q(kk + 1, bsel ^ 1);
        const short* Ab = &As[bsel][((wv & 1) * 64 + col) * 32 + quad * 8];
        const short* Bb = &Bs[bsel][((wv >> 1) * 64 + col) * 32 + quad * 8];
        bf16x8 af[4], bfr[4];
#pragma unroll
        for (int i = 0; i < 4; ++i) {
            af[i]  = *(const bf16x8*)(Ab + i * 512);
            bfr[i] = *(const bf16x8*)(Bb + i * 512);
        }
#pragma unroll
        for (int mt = 0; mt < 4; ++mt)
#pragma unroll
            for (int nt = 0; nt < 4; ++nt)
                acc[mt][nt] = __builtin_amdgcn_mfma_f32_16x16x32_bf16(af[mt], bfr[nt], acc[mt][nt], 0, 0, 0);
        bsel ^= 1;
    }

    const float qs = 0.25503000508221157f;   // log2(e)/sqrt(32)
#pragma unroll
    for (int mt = 0; mt < 4; ++mt) {
        const int cocat = m0 + (wv & 1) * 64 + mt * 16 + quad * 4;
        const int co = cocat & 255;
        const int hh = co >> 5, d = co & 31;
        const size_t bh = (size_t)b * HDIM + hh;
#pragma unroll
        for (int nt = 0; nt < 4; ++nt) {
            const int t = t0 + (wv >> 1) * 64 + nt * 16 + col;
            const f32x4 a = acc[mt][nt];
            if (qkv == 0) {
                uint2 u = make_uint2(pk2(a[0] * qs, a[1] * qs), pk2(a[2] * qs, a[3] * qs));
                *(uint2*)(qo + (bh * TDIM + t) * DDIM + d) = u;
            } else if (qkv == 1) {
                uint2 u = make_uint2(pk2(a[0], a[1]), pk2(a[2], a[3]));
                *(uint2*)(ko + (bh * TDIM + t) * DDIM + d) = u;
            } else {
                const int kt = t >> 6, u6 = t & 63, kg = u6 >> 5, rr = u6 & 31;
                const int j = ((rr >> 4) << 2) | (rr & 3), qd = (rr >> 2) & 3;
                short* vb2 = vt2 + ((bh * 32 + kt) * 2 + kg) * 1024 + qd * 8 + j;
#pragma unroll
                for (int r = 0; r < 4; ++r) vb2[(d + r) * 32] = bf1(a[r]);
            }
        }
    }
#undef STAGE_Q
}

// ---------------------------------------------------------------------------
// Output conv + residual. Tile 64t x 128co -> grid (256,2) = 512 blocks =
// 2 blocks/CU (verified win R11: total 188.7 -> 176.1). LDS 24KB dbuf.
// ---------------------------------------------------------------------------
__global__ __launch_bounds__(256) void gemm_res(
    const short* __restrict__ cp, const short* __restrict__ wot,
    const float* __restrict__ bo, const float* __restrict__ x,
    float* __restrict__ out)
{
    __shared__ short As[2][4096];
    __shared__ short Bs[2][2048];
    const int tid = threadIdx.x;
    const int wv = tid >> 6, lane = tid & 63, quad = lane >> 4, col = lane & 15;
    const int bx = blockIdx.x;
    const int b = bx >> 5, t0 = (bx & 31) * 64;
    const int m0 = blockIdx.y * 128;

    const short* wA = wot + (size_t)m0 * 768;
    const short* cB = cp + ((size_t)b * TP + t0) * CDIM;
    const int r0 = tid >> 2, s0 = (tid & 3) * 8;

#define STAGE_R(kk, bsel) do {                                                  \
    const int dt_ = (kk) >> 3, ci0_ = ((kk) & 7) * 32, k0_ = (kk) * 32;         \
    gld16(wA + (size_t)r0 * 768 + k0_ + s0,        &As[bsel][tid * 8]);         \
    gld16(wA + (size_t)(r0 + 64) * 768 + k0_ + s0, &As[bsel][tid * 8 + 2048]);  \
    gld16(cB + (size_t)(r0 + dt_) * 256 + ci0_ + s0,      &Bs[bsel][tid * 8]);  \
} while (0)

    STAGE_R(0, 0);

    f32x4 acc[4][2];
#pragma unroll
    for (int mt = 0; mt < 4; ++mt) {
        const int cb = m0 + (wv & 1) * 64 + mt * 16 + quad * 4;
        const float4 b4 = *(const float4*)(bo + cb);
#pragma unroll
        for (int nt = 0; nt < 2; ++nt) acc[mt][nt] = (f32x4){b4.x, b4.y, b4.z, b4.w};
    }

    int bsel = 0;
    for (int kk = 0; kk < 24; ++kk) {
        __syncthreads();
        if (kk < 23) STAGE_R(kk + 1, bsel ^ 1);
        const short* Ab = &As[bsel][((wv & 1) * 64 + col) * 32 + quad * 8];
        const short* Bb = &Bs[bsel][((wv >> 1) * 32 + col) * 32 + quad * 8];
        bf16x8 af[4], bfr[2];
#pragma unroll
        for (int i = 0; i < 4; ++i) af[i]  = *(const bf16x8*)(Ab + i * 512);
#pragma unroll
        for (int i = 0; i < 2; ++i) bfr[i] = *(const bf16x8*)(Bb + i * 512);
#pragma unroll
        for (int mt = 0; mt < 4; ++mt)
#pragma unroll
            for (int nt = 0; nt < 2; ++nt)
                acc[mt][nt] = __builtin_amdgcn_mfma_f32_16x16x32_bf16(af[mt], bfr[nt], acc[mt][nt], 0, 0, 0);
        bsel ^= 1;
    }

#pragma unroll
    for (int mt = 0; mt < 4; ++mt) {
        const int co = m0 + (wv & 1) * 64 + mt * 16 + quad * 4;
#pragma unroll
        for (int nt = 0; nt < 2; ++nt) {
            const int t = t0 + (wv >> 1) * 32 + nt * 16 + col;
            const size_t o = ((size_t)b * TDIM + t) * CDIM + co;
            const float4 xv = *(const float4*)(x + o);
            const f32x4 a = acc[mt][nt];
            *(float4*)(out + o) = make_float4(a[0] + xv.x, a[1] + xv.y, a[2] + xv.z, a[3] + xv.w);
        }
    }
#undef STAGE_R
}

// ---------------------------------------------------------------------------
// MFMA flash attention — R7-exact (verified deterministic, ~50us).
// Reg-staged ds_write + one barrier per 64-key tile, swizzled LDS
// (conflict-free, verified 0), pipelined QK(q0)+QK(q1) -> exp(A) -> PV(A) ->
// exp(B) -> PV(B). No setprio. S^T trick (A=K, B=Q); l via ones-A-frag MFMA;
// raw v_exp_f32 (q pre-scaled by log2e/sqrt(D)).
// Five structural variants (R1/R5/R7/R8 + reorder) all land 49-54us with
// invariant VALU~23us / MFMA~16us: consistent with the ~27us trans-pipe
// floor of 268M v_exp_f32 at quarter rate. Declared local floor.
// ---------------------------------------------------------------------------
__global__ __launch_bounds__(256, 4) void attn_kernel(
    const short* __restrict__ q, const short* __restrict__ k,
    const short* __restrict__ vt2, short* __restrict__ cp)
{
    __shared__ short ks[2][2048];
    __shared__ short vs[2][2048];
    const int tid = threadIdx.x;
    const int wv = tid >> 6, lane = tid & 63, quad = lane >> 4, col = lane & 15;
    const int bh = blockIdx.x;                    // XCD-locality: bh fixes XCD
    const int q0 = blockIdx.y * 128 + wv * 32;

    const short* qb = q + (size_t)bh * TDIM * DDIM;
    const short* kb = k + (size_t)bh * TDIM * DDIM;
    const short* vb = vt2 + (size_t)bh * TDIM * DDIM;
    const int so = tid * 8;                       // global staging offset (shorts)
    // swizzled LDS staging offset: row=tid>>2, slot=(tid&3)^((tid>>3)&3)
    const int sw = (tid >> 2) * 32 + (((tid & 3) ^ ((tid >> 3) & 3)) << 3);

    // stage tile 0 (regs -> LDS, swizzled)
    {
        uint4 kr = *(const uint4*)(kb + so);
        uint4 vr = *(const uint4*)(vb + so);
        *(uint4*)&ks[0][sw] = kr;
        *(uint4*)&vs[0][sw] = vr;
    }

    bf16x8 qf0 = *(const bf16x8*)(qb + (size_t)(q0 + col) * DDIM + quad * 8);
    bf16x8 qf1 = *(const bf16x8*)(qb + (size_t)(q0 + 16 + col) * DDIM + quad * 8);

    f32x4 acc0_0 = {0.f,0.f,0.f,0.f}, acc0_1 = {0.f,0.f,0.f,0.f};
    f32x4 acc1_0 = {0.f,0.f,0.f,0.f}, acc1_1 = {0.f,0.f,0.f,0.f};
    f32x4 accl_0 = {0.f,0.f,0.f,0.f}, accl_1 = {0.f,0.f,0.f,0.f};
    const f32x4 zero = {0.f, 0.f, 0.f, 0.f};
    const short one_bf = (short)0x3F80;   // bf16 1.0
    const bf16x8 ones = {one_bf, one_bf, one_bf, one_bf, one_bf, one_bf, one_bf, one_bf};

    // swizzled frag offset within tile: row=g*16+col, slot'=quad^((col>>1)&3)
    const int foff = col * 32 + ((quad ^ ((col >> 1) & 3)) << 3);

    union Pu { unsigned u[4]; bf16x8 v; };

#define MFMA(a_, b_, c_) __builtin_amdgcn_mfma_f32_16x16x32_bf16(a_, b_, c_, 0, 0, 0)

// exp+pack 16 f32 (4 frags) -> two bf16x8 B-operands
#define EXPPACK(s0_, s1_, s2_, s3_, PP0, PP1) do {                         \
    float e0 = EXP2(s0_[0]), e1 = EXP2(s0_[1]), e2 = EXP2(s0_[2]), e3 = EXP2(s0_[3]); \
    float e4 = EXP2(s1_[0]), e5 = EXP2(s1_[1]), e6 = EXP2(s1_[2]), e7 = EXP2(s1_[3]); \
    float e8 = EXP2(s2_[0]), e9 = EXP2(s2_[1]), eA = EXP2(s2_[2]), eB = EXP2(s2_[3]); \
    float eC = EXP2(s3_[0]), eD = EXP2(s3_[1]), eE = EXP2(s3_[2]), eF = EXP2(s3_[3]); \
    PP0.u[0] = pk2t(e0, e1); PP0.u[1] = pk2t(e2, e3);                      \
    PP0.u[2] = pk2t(e4, e5); PP0.u[3] = pk2t(e6, e7);                      \
    PP1.u[0] = pk2t(e8, e9); PP1.u[1] = pk2t(eA, eB);                      \
    PP1.u[2] = pk2t(eC, eD); PP1.u[3] = pk2t(eE, eF);                      \
} while (0)

// 6-MFMA PV step into one q-slot's accumulators
#define PVSTEP(A0, A1, AL, PP0, PP1) do {                                  \
    A0 = MFMA(v0, PP0.v, A0);  A1 = MFMA(v1, PP0.v, A1);                   \
    AL = MFMA(ones, PP0.v, AL);                                            \
    A0 = MFMA(v2, PP1.v, A0);  A1 = MFMA(v3, PP1.v, A1);                   \
    AL = MFMA(ones, PP1.v, AL);                                            \
} while (0)

    __syncthreads();                              // tile 0 visible

    for (int kt = 0; kt < TDIM / 64; ++kt) {
        const int cur = kt & 1;
        // issue next tile's global loads FIRST (hidden under compute below)
        uint4 krn, vrn;
        const bool more = kt < TDIM / 64 - 1;
        if (more) {
            krn = *(const uint4*)(kb + (kt + 1) * 2048 + so);
            vrn = *(const uint4*)(vb + (kt + 1) * 2048 + so);
        }
        const short* kbase = &ks[cur][foff];
        const short* vbase = &vs[cur][foff];
        bf16x8 k0 = *(const bf16x8*)(kbase +    0), k1 = *(const bf16x8*)(kbase +  512);
        bf16x8 k2 = *(const bf16x8*)(kbase + 1024), k3 = *(const bf16x8*)(kbase + 1536);
        bf16x8 v0 = *(const bf16x8*)(vbase +    0), v1 = *(const bf16x8*)(vbase +  512);
        bf16x8 v2 = *(const bf16x8*)(vbase + 1024), v3 = *(const bf16x8*)(vbase + 1536);
        // QK for BOTH q-slots back-to-back: 8 independent MFMAs fill the pipe
        f32x4 sA0 = MFMA(k0, qf0, zero), sA1 = MFMA(k1, qf0, zero);
        f32x4 sA2 = MFMA(k2, qf0, zero), sA3 = MFMA(k3, qf0, zero);
        f32x4 sB0 = MFMA(k0, qf1, zero), sB1 = MFMA(k1, qf1, zero);
        f32x4 sB2 = MFMA(k2, qf1, zero), sB3 = MFMA(k3, qf1, zero);
        // exp/pack(A) on VALU while QK(B) drains on matrix pipe
        Pu PA0, PA1;
        EXPPACK(sA0, sA1, sA2, sA3, PA0, PA1);
        // PV(A) on matrix pipe while exp/pack(B) runs on VALU
        PVSTEP(acc0_0, acc1_0, accl_0, PA0, PA1);
        Pu PB0, PB1;
        EXPPACK(sB0, sB1, sB2, sB3, PB0, PB1);
        PVSTEP(acc0_1, acc1_1, accl_1, PB0, PB1);
        // ds_write staged tile kt+1 (buffer cur^1: its readers sealed by the
        // barrier at end of iteration kt-1)
        if (more) {
            *(uint4*)&ks[cur ^ 1][sw] = krn;
            *(uint4*)&vs[cur ^ 1][sw] = vrn;
        }
        __syncthreads();   // seals: my tile-(kt+1) writes visible; all reads of cur done
    }

    const int b = bh >> 3, hh = bh & 7;
    {
        const float inv = 1.f / accl_0[0];   // full-key sum, identical in all regs
        const int t = q0 + col;
        short* crow = cp + ((size_t)b * TP + t + 1) * CDIM + hh * DDIM;
        uint2 u0 = make_uint2(pk2(acc0_0[0] * inv, acc0_0[1] * inv),
                              pk2(acc0_0[2] * inv, acc0_0[3] * inv));
        uint2 u1 = make_uint2(pk2(acc1_0[0] * inv, acc1_0[1] * inv),
                              pk2(acc1_0[2] * inv, acc1_0[3] * inv));
        *(uint2*)(crow + quad * 4)      = u0;
        *(uint2*)(crow + 16 + quad * 4) = u1;
    }
    {
        const float inv = 1.f / accl_1[0];
        const int t = q0 + 16 + col;
        short* crow = cp + ((size_t)b * TP + t + 1) * CDIM + hh * DDIM;
        uint2 u0 = make_uint2(pk2(acc0_1[0] * inv, acc0_1[1] * inv),
                              pk2(acc0_1[2] * inv, acc0_1[3] * inv));
        uint2 u1 = make_uint2(pk2(acc1_1[0] * inv, acc1_1[1] * inv),
                              pk2(acc1_1[2] * inv, acc1_1[3] * inv));
        *(uint2*)(crow + quad * 4)      = u0;
        *(uint2*)(crow + 16 + quad * 4) = u1;
    }
#undef MFMA
#undef EXPPACK
#undef PVSTEP
}

// ---------------------------------------------------------------------------
extern "C" void kernel_launch(void* const* d_in, const int* in_sizes, int n_in,
                              void* d_out, int out_size, void* d_ws, size_t ws_size,
                              hipStream_t stream) {
    const float* x  = (const float*)d_in[0];
    const float* Wq = (const float*)d_in[1];
    const float* bq = (const float*)d_in[2];
    const float* Wk = (const float*)d_in[3];
    const float* bk = (const float*)d_in[4];
    const float* Wv = (const float*)d_in[5];
    const float* bv = (const float*)d_in[6];
    const float* Wo = (const float*)d_in[7];
    const float* bo = (const float*)d_in[8];
    float* out = (float*)d_out;

    short* p = (short*)d_ws;
    short* xbfp = p; p += (size_t)BDIM * TP * CDIM;        // 4,198,400
    short* cpb  = p; p += (size_t)BDIM * TP * CDIM;        // 4,198,400
    short* qbuf = p; p += (size_t)BDIM * HDIM * TDIM * DDIM; // 4,194,304
    short* kbuf = p; p += (size_t)BDIM * HDIM * TDIM * DDIM;
    short* vt2  = p; p += (size_t)BDIM * HDIM * TDIM * DDIM;
    short* wcat = p; p += 768 * 768;
    short* wot  = p; p += 256 * 768;
    // total ~43.5 MB

    prep_kernel<<<dim3(XBLK + WBLK), 256, 0, stream>>>(x, Wq, Wk, Wv, Wo, xbfp, cpb, wcat, wot);
    gemm_qkv<<<dim3(128, 6), 256, 0, stream>>>(xbfp, wcat, bq, bk, bv, qbuf, kbuf, vt2);
    attn_kernel<<<dim3(64, 16), 256, 0, stream>>>(qbuf, kbuf, vt2, cpb);
    gemm_res<<<dim3(256, 2), 256, 0, stream>>>(cpb, wot, bo, x, out);
}

// Round 15
// 170.347 us; speedup vs baseline: 1.1077x; 1.0320x over previous
//
#include <hip/hip_runtime.h>
#include <math.h>

// Problem constants (fixed by reference)
#define BDIM 8
#define TDIM 2048
#define CDIM 256
#define HDIM 8
#define DDIM 32
#define TP   (TDIM + 2)   // padded time (halo row above and below, zeroed)

typedef __attribute__((ext_vector_type(8))) short bf16x8;   // MFMA A/B frag (4 VGPR)
typedef __attribute__((ext_vector_type(4))) float f32x4;    // MFMA C/D frag

#if __has_builtin(__builtin_amdgcn_exp2f)
#define EXP2(x) __builtin_amdgcn_exp2f(x)
#else
#define EXP2(x) exp2f(x)
#endif

// pack two f32 -> one dword of two bf16 (round-half-up: +0x8000 then v_perm)
__device__ __forceinline__ unsigned pk2(float lo, float hi) {
    union { float f; unsigned u; } a, b;
    a.f = lo; b.f = hi;
    return __builtin_amdgcn_perm(b.u + 0x8000u, a.u + 0x8000u, 0x07060302u);
}
// truncating pack (1 op). For p >= 0 the <=0.8% downward bias cancels between
// softmax numerator and denominator (l is summed from the SAME bf16 values).
__device__ __forceinline__ unsigned pk2t(float lo, float hi) {
    union { float f; unsigned u; } a, b;
    a.f = lo; b.f = hi;
    return __builtin_amdgcn_perm(b.u, a.u, 0x07060302u);
}
__device__ __forceinline__ short bf1(float v) {
    union { float f; unsigned u; } a; a.f = v;
    return (short)((a.u + 0x8000u) >> 16);
}
// async global->LDS, 16B per lane (dest must be wave-uniform base + lane*16)
__device__ __forceinline__ void gld16(const short* g, short* l) {
    __builtin_amdgcn_global_load_lds((const __attribute__((address_space(1))) void*)g,
                                     (__attribute__((address_space(3))) void*)l, 16, 0, 0);
}

#define XBLK 832   // prep: blocks doing x-convert + halos
#define WBLK 192   // prep: blocks doing LDS-tiled weight transpose (12 pairs x 16)

// ---------------------------------------------------------------------------
// Prep: x -> bf16 padded xbfp[B][TP][C] (halos zero); weights -> bf16 W^T
// (row=co, col=k=dt*256+ci) via LDS-tiled transpose (coalesced both sides).
// ---------------------------------------------------------------------------
__global__ __launch_bounds__(256) void prep_kernel(
    const float* __restrict__ x,
    const float* __restrict__ Wq, const float* __restrict__ Wk,
    const float* __restrict__ Wv, const float* __restrict__ Wo,
    short* __restrict__ xbfp, short* __restrict__ cp,
    short* __restrict__ wcat, short* __restrict__ wot)
{
    const int tid = threadIdx.x;
    if (blockIdx.x < XBLK) {
        const int NX = BDIM * TDIM * 64;    // float4 chunks of x
        const int NH = 4096;                // halo dwords (xbfp + cp)
        unsigned* xw = (unsigned*)xbfp;
        unsigned* cw = (unsigned*)cp;
        for (int i = blockIdx.x * 256 + tid; i < NX + NH; i += XBLK * 256) {
            if (i < NX) {
                const int bt = i >> 6, c4 = i & 63;
                const int b = bt >> 11, t = bt & 2047;
                const float4 f = *(const float4*)(x + (size_t)bt * 256 + c4 * 4);
                const size_t wo_ = (size_t)(b * TP + t + 1) * 128 + c4 * 2;
                xw[wo_]     = pk2(f.x, f.y);
                xw[wo_ + 1] = pk2(f.z, f.w);
            } else {
                const int hz = i - NX;
                const int half = hz >> 11, z = hz & 2047;
                const int b = z >> 8, r = (z >> 7) & 1, wofs = z & 127;
                const size_t w_ = ((size_t)b * TP + (size_t)r * (TP - 1)) * 128 + wofs;
                if (half == 0) xw[w_] = 0u; else cw[w_] = 0u;
            }
        }
    } else {
        // weight transpose: 12 (dt,mat) pairs x 16 subtiles of 64ci x 64co
        __shared__ float xs[64][65];
        const int wb = blockIdx.x - XBLK;
        const int pair = wb >> 4, sub = wb & 15;
        const int dt = pair >> 2, mat = pair & 3;        // mat: 0=q 1=k 2=v 3=o
        const int ci0 = (sub >> 2) * 64, co0 = (sub & 3) * 64;
        const float* W = mat == 0 ? Wq : mat == 1 ? Wk : mat == 2 ? Wv : Wo;
        const float* src = W + dt * 65536 + (size_t)ci0 * 256 + co0;
        for (int idx = tid; idx < 4096; idx += 256) {
            const int r = idx >> 6, c = idx & 63;
            xs[r][c] = src[(size_t)r * 256 + c];
        }
        __syncthreads();
        short* dstbase = (mat < 3) ? (wcat + (size_t)(mat * 256 + co0) * 768)
                                   : (wot + (size_t)co0 * 768);
        for (int idx = tid; idx < 512; idx += 256) {
            const int co_l = idx >> 3, ci_l = (idx & 7) * 8;
            uint4 u;
            u.x = pk2(xs[ci_l + 0][co_l], xs[ci_l + 1][co_l]);
            u.y = pk2(xs[ci_l + 2][co_l], xs[ci_l + 3][co_l]);
            u.z = pk2(xs[ci_l + 4][co_l], xs[ci_l + 5][co_l]);
            u.w = pk2(xs[ci_l + 6][co_l], xs[ci_l + 7][co_l]);
            *(uint4*)(dstbase + (size_t)co_l * 768 + dt * 256 + ci0 + ci_l) = u;
        }
    }
}

// ---------------------------------------------------------------------------
// QKV conv as double-buffered MFMA GEMM (m97 structure).
// Result transposed: A = W rows (m=co_cat), B = x rows (n=t).
// Block 256 thr = 4 waves; tile 128 co x 128 t; BK=32 (k = dt*256+ci, chunks
// never straddle dt). grid (128 t-tiles, 6 co-tiles); blockIdx.y>>1 = q/k/v.
// launch_bounds(256,4): measured null (R14) -> VGPR already <=128; harmless.
// ---------------------------------------------------------------------------
__global__ __launch_bounds__(256, 4) void gemm_qkv(
    const short* __restrict__ xbfp, const short* __restrict__ wcat,
    const float* __restrict__ bq, const float* __restrict__ bk,
    const float* __restrict__ bv,
    short* __restrict__ qo, short* __restrict__ ko, short* __restrict__ vt2)
{
    __shared__ short As[2][4096];
    __shared__ short Bs[2][4096];
    const int tid = threadIdx.x;
    const int wv = tid >> 6, lane = tid & 63, quad = lane >> 4, col = lane & 15;
    const int bx = blockIdx.x;
    const int b = bx >> 4, t0 = (bx & 15) * 128;
    const int by = blockIdx.y;
    const int qkv = by >> 1;
    const int m0 = by * 128;

    const short* wA = wcat + (size_t)m0 * 768;
    const short* xB = xbfp + ((size_t)b * TP + t0) * CDIM;
    const int r0 = tid >> 2, s0 = (tid & 3) * 8;   // chunk row / in-row offset

#define STAGE_Q(kk, bsel) do {                                                  \
    const int dt_ = (kk) >> 3, ci0_ = ((kk) & 7) * 32, k0_ = (kk) * 32;         \
    gld16(wA + (size_t)r0 * 768 + k0_ + s0,        &As[bsel][tid * 8]);         \
    gld16(wA + (size_t)(r0 + 64) * 768 + k0_ + s0, &As[bsel][tid * 8 + 2048]);  \
    gld16(xB + (size_t)(r0 + dt_) * 256 + ci0_ + s0,      &Bs[bsel][tid * 8]);  \
    gld16(xB + (size_t)(r0 + 64 + dt_) * 256 + ci0_ + s0, &Bs[bsel][tid * 8 + 2048]); \
} while (0)

    STAGE_Q(0, 0);

    const float* bias = qkv == 0 ? bq : qkv == 1 ? bk : bv;
    f32x4 acc[4][4];
#pragma unroll
    for (int mt = 0; mt < 4; ++mt) {
        const int cb = ((m0 + (wv & 1) * 64 + mt * 16) & 255) + quad * 4;
        const float4 b4 = *(const float4*)(bias + cb);
#pragma unroll
        for (int nt = 0; nt < 4; ++nt) acc[mt][nt] = (f32x4){b4.x, b4.y, b4.z, b4.w};
    }

    int bsel = 0;
    for (int kk = 0; kk < 24; ++kk) {
        __syncthreads();
        if (kk < 23) STAGE_Q(kk + 1, bsel ^ 1);
        const short* Ab = &As[bsel][((wv & 1) * 64 + col) * 32 + quad * 8];
        const short* Bb = &Bs[bsel][((wv >> 1) * 64 + col) * 32 + quad * 8];
        bf16x8 af[4], bfr[4];
#pragma unroll
        for (int i = 0; i < 4; ++i) {
            af[i]  = *(const bf16x8*)(Ab + i * 512);
            bfr[i] = *(const bf16x8*)(Bb + i * 512);
        }
#pragma unroll
        for (int mt = 0; mt < 4; ++mt)
#pragma unroll
            for (int nt = 0; nt < 4; ++nt)
                acc[mt][nt] = __builtin_amdgcn_mfma_f32_16x16x32_bf16(af[mt], bfr[nt], acc[mt][nt], 0, 0, 0);
        bsel ^= 1;
    }

    const float qs = 0.25503000508221157f;   // log2(e)/sqrt(32)
#pragma unroll
    for (int mt = 0; mt < 4; ++mt) {
        const int cocat = m0 + (wv & 1) * 64 + mt * 16 + quad * 4;
        const int co = cocat & 255;
        const int hh = co >> 5, d = co & 31;
        const size_t bh = (size_t)b * HDIM + hh;
#pragma unroll
        for (int nt = 0; nt < 4; ++nt) {
            const int t = t0 + (wv >> 1) * 64 + nt * 16 + col;
            const f32x4 a = acc[mt][nt];
            if (qkv == 0) {
                uint2 u = make_uint2(pk2(a[0] * qs, a[1] * qs), pk2(a[2] * qs, a[3] * qs));
                *(uint2*)(qo + (bh * TDIM + t) * DDIM + d) = u;
            } else if (qkv == 1) {
                uint2 u = make_uint2(pk2(a[0], a[1]), pk2(a[2], a[3]));
                *(uint2*)(ko + (bh * TDIM + t) * DDIM + d) = u;
            } else {
                const int kt = t >> 6, u6 = t & 63, kg = u6 >> 5, rr = u6 & 31;
                const int j = ((rr >> 4) << 2) | (rr & 3), qd = (rr >> 2) & 3;
                short* vb2 = vt2 + ((bh * 32 + kt) * 2 + kg) * 1024 + qd * 8 + j;
#pragma unroll
                for (int r = 0; r < 4; ++r) vb2[(d + r) * 32] = bf1(a[r]);
            }
        }
    }
#undef STAGE_Q
}

// ---------------------------------------------------------------------------
// Output conv + residual. Tile 64t x 128co -> grid (256,2) = 512 blocks =
// 2 blocks/CU (verified win R11: total 188.7 -> 176.1). LDS 24KB dbuf.
// ---------------------------------------------------------------------------
__global__ __launch_bounds__(256) void gemm_res(
    const short* __restrict__ cp, const short* __restrict__ wot,
    const float* __restrict__ bo, const float* __restrict__ x,
    float* __restrict__ out)
{
    __shared__ short As[2][4096];
    __shared__ short Bs[2][2048];
    const int tid = threadIdx.x;
    const int wv = tid >> 6, lane = tid & 63, quad = lane >> 4, col = lane & 15;
    const int bx = blockIdx.x;
    const int b = bx >> 5, t0 = (bx & 31) * 64;
    const int m0 = blockIdx.y * 128;

    const short* wA = wot + (size_t)m0 * 768;
    const short* cB = cp + ((size_t)b * TP + t0) * CDIM;
    const int r0 = tid >> 2, s0 = (tid & 3) * 8;

#define STAGE_R(kk, bsel) do {                                                  \
    const int dt_ = (kk) >> 3, ci0_ = ((kk) & 7) * 32, k0_ = (kk) * 32;         \
    gld16(wA + (size_t)r0 * 768 + k0_ + s0,        &As[bsel][tid * 8]);         \
    gld16(wA + (size_t)(r0 + 64) * 768 + k0_ + s0, &As[bsel][tid * 8 + 2048]);  \
    gld16(cB + (size_t)(r0 + dt_) * 256 + ci0_ + s0,      &Bs[bsel][tid * 8]);  \
} while (0)

    STAGE_R(0, 0);

    f32x4 acc[4][2];
#pragma unroll
    for (int mt = 0; mt < 4; ++mt) {
        const int cb = m0 + (wv & 1) * 64 + mt * 16 + quad * 4;
        const float4 b4 = *(const float4*)(bo + cb);
#pragma unroll
        for (int nt = 0; nt < 2; ++nt) acc[mt][nt] = (f32x4){b4.x, b4.y, b4.z, b4.w};
    }

    int bsel = 0;
    for (int kk = 0; kk < 24; ++kk) {
        __syncthreads();
        if (kk < 23) STAGE_R(kk + 1, bsel ^ 1);
        const short* Ab = &As[bsel][((wv & 1) * 64 + col) * 32 + quad * 8];
        const short* Bb = &Bs[bsel][((wv >> 1) * 32 + col) * 32 + quad * 8];
        bf16x8 af[4], bfr[2];
#pragma unroll
        for (int i = 0; i < 4; ++i) af[i]  = *(const bf16x8*)(Ab + i * 512);
#pragma unroll
        for (int i = 0; i < 2; ++i) bfr[i] = *(const bf16x8*)(Bb + i * 512);
#pragma unroll
        for (int mt = 0; mt < 4; ++mt)
#pragma unroll
            for (int nt = 0; nt < 2; ++nt)
                acc[mt][nt] = __builtin_amdgcn_mfma_f32_16x16x32_bf16(af[mt], bfr[nt], acc[mt][nt], 0, 0, 0);
        bsel ^= 1;
    }

#pragma unroll
    for (int mt = 0; mt < 4; ++mt) {
        const int co = m0 + (wv & 1) * 64 + mt * 16 + quad * 4;
#pragma unroll
        for (int nt = 0; nt < 2; ++nt) {
            const int t = t0 + (wv >> 1) * 32 + nt * 16 + col;
            const size_t o = ((size_t)b * TDIM + t) * CDIM + co;
            const float4 xv = *(const float4*)(x + o);
            const f32x4 a = acc[mt][nt];
            *(float4*)(out + o) = make_float4(a[0] + xv.x, a[1] + xv.y, a[2] + xv.z, a[3] + xv.w);
        }
    }
#undef STAGE_R
}

// ---------------------------------------------------------------------------
// MFMA flash attention, R15: 4 chains/wave (q-tile 256/block).
// Memory structure byte-identical to R7 (reg-staged ds_write + one barrier,
// KVBLK=64, swizzled LDS, verified deterministic & conflict-free). Change:
// each wave owns 64 q-rows (4 MFMA slots) instead of 32 (2). Mechanism:
// the 6-structure-invariant stall is chain latency (QK->exp->PV serial chain,
// only 2 independent chains/phase; R7 showed reordering 2 chains is null;
// R8 showed more waves with same chains/wave is worse due to 2x staging).
// 4 chains/phase gives the scheduler twice the independent work between
// barriers AND halves per-unit-work staging + barriers (grid 1024->512 =
// 2 blocks/CU exactly; launch_bounds(256,2) -> 256-VGPR headroom, no spill
// at est. ~180 live).
// S^T trick (A=K, B=Q); l via ones-A-frag MFMA; raw v_exp_f32 (q pre-scaled
// by log2e/sqrt(D)). Grid (bh, qtile): bh fixes the XCD, K/V L2-resident.
// ---------------------------------------------------------------------------
__global__ __launch_bounds__(256, 2) void attn_kernel(
    const short* __restrict__ q, const short* __restrict__ k,
    const short* __restrict__ vt2, short* __restrict__ cp)
{
    __shared__ short ks[2][2048];
    __shared__ short vs[2][2048];
    const int tid = threadIdx.x;
    const int wv = tid >> 6, lane = tid & 63, quad = lane >> 4, col = lane & 15;
    const int bh = blockIdx.x;                    // XCD-locality: bh fixes XCD
    const int q0 = blockIdx.y * 256 + wv * 64;    // 64 q-rows per wave

    const short* qb = q + (size_t)bh * TDIM * DDIM;
    const short* kb = k + (size_t)bh * TDIM * DDIM;
    const short* vb = vt2 + (size_t)bh * TDIM * DDIM;
    const int so = tid * 8;                       // global staging offset (shorts)
    // swizzled LDS staging offset: row=tid>>2, slot=(tid&3)^((tid>>3)&3)
    const int sw = (tid >> 2) * 32 + (((tid & 3) ^ ((tid >> 3) & 3)) << 3);

    // stage tile 0 (regs -> LDS, swizzled)
    {
        uint4 kr = *(const uint4*)(kb + so);
        uint4 vr = *(const uint4*)(vb + so);
        *(uint4*)&ks[0][sw] = kr;
        *(uint4*)&vs[0][sw] = vr;
    }

    bf16x8 qf0 = *(const bf16x8*)(qb + (size_t)(q0 + col) * DDIM + quad * 8);
    bf16x8 qf1 = *(const bf16x8*)(qb + (size_t)(q0 + 16 + col) * DDIM + quad * 8);
    bf16x8 qf2 = *(const bf16x8*)(qb + (size_t)(q0 + 32 + col) * DDIM + quad * 8);
    bf16x8 qf3 = *(const bf16x8*)(qb + (size_t)(q0 + 48 + col) * DDIM + quad * 8);

    f32x4 acc0_0 = {0.f,0.f,0.f,0.f}, acc0_1 = {0.f,0.f,0.f,0.f};
    f32x4 acc0_2 = {0.f,0.f,0.f,0.f}, acc0_3 = {0.f,0.f,0.f,0.f};
    f32x4 acc1_0 = {0.f,0.f,0.f,0.f}, acc1_1 = {0.f,0.f,0.f,0.f};
    f32x4 acc1_2 = {0.f,0.f,0.f,0.f}, acc1_3 = {0.f,0.f,0.f,0.f};
    f32x4 accl_0 = {0.f,0.f,0.f,0.f}, accl_1 = {0.f,0.f,0.f,0.f};
    f32x4 accl_2 = {0.f,0.f,0.f,0.f}, accl_3 = {0.f,0.f,0.f,0.f};
    const f32x4 zero = {0.f, 0.f, 0.f, 0.f};
    const short one_bf = (short)0x3F80;   // bf16 1.0
    const bf16x8 ones = {one_bf, one_bf, one_bf, one_bf, one_bf, one_bf, one_bf, one_bf};

    // swizzled frag offset within tile: row=g*16+col, slot'=quad^((col>>1)&3)
    const int foff = col * 32 + ((quad ^ ((col >> 1) & 3)) << 3);

    union Pu { unsigned u[4]; bf16x8 v; };

#define MFMA(a_, b_, c_) __builtin_amdgcn_mfma_f32_16x16x32_bf16(a_, b_, c_, 0, 0, 0)

// exp+pack 16 f32 (4 frags) -> two bf16x8 B-operands
#define EXPPACK(s0_, s1_, s2_, s3_, PP0, PP1) do {                         \
    float e0 = EXP2(s0_[0]), e1 = EXP2(s0_[1]), e2 = EXP2(s0_[2]), e3 = EXP2(s0_[3]); \
    float e4 = EXP2(s1_[0]), e5 = EXP2(s1_[1]), e6 = EXP2(s1_[2]), e7 = EXP2(s1_[3]); \
    float e8 = EXP2(s2_[0]), e9 = EXP2(s2_[1]), eA = EXP2(s2_[2]), eB = EXP2(s2_[3]); \
    float eC = EXP2(s3_[0]), eD = EXP2(s3_[1]), eE = EXP2(s3_[2]), eF = EXP2(s3_[3]); \
    PP0.u[0] = pk2t(e0, e1); PP0.u[1] = pk2t(e2, e3);                      \
    PP0.u[2] = pk2t(e4, e5); PP0.u[3] = pk2t(e6, e7);                      \
    PP1.u[0] = pk2t(e8, e9); PP1.u[1] = pk2t(eA, eB);                      \
    PP1.u[2] = pk2t(eC, eD); PP1.u[3] = pk2t(eE, eF);                      \
} while (0)

// 6-MFMA PV step into one q-slot's accumulators
#define PVSTEP(A0, A1, AL, PP0, PP1) do {                                  \
    A0 = MFMA(v0, PP0.v, A0);  A1 = MFMA(v1, PP0.v, A1);                   \
    AL = MFMA(ones, PP0.v, AL);                                            \
    A0 = MFMA(v2, PP1.v, A0);  A1 = MFMA(v3, PP1.v, A1);                   \
    AL = MFMA(ones, PP1.v, AL);                                            \
} while (0)

    __syncthreads();                              // tile 0 visible

    for (int kt = 0; kt < TDIM / 64; ++kt) {
        const int cur = kt & 1;
        // issue next tile's global loads FIRST (hidden under compute below)
        uint4 krn, vrn;
        const bool more = kt < TDIM / 64 - 1;
        if (more) {
            krn = *(const uint4*)(kb + (kt + 1) * 2048 + so);
            vrn = *(const uint4*)(vb + (kt + 1) * 2048 + so);
        }
        const short* kbase = &ks[cur][foff];
        const short* vbase = &vs[cur][foff];
        bf16x8 k0 = *(const bf16x8*)(kbase +    0), k1 = *(const bf16x8*)(kbase +  512);
        bf16x8 k2 = *(const bf16x8*)(kbase + 1024), k3 = *(const bf16x8*)(kbase + 1536);
        bf16x8 v0 = *(const bf16x8*)(vbase +    0), v1 = *(const bf16x8*)(vbase +  512);
        bf16x8 v2 = *(const bf16x8*)(vbase + 1024), v3 = *(const bf16x8*)(vbase + 1536);
        // ---- pair (q0,q1): 8 independent QK MFMAs, then exp/PV interleave
        {
            f32x4 sA0 = MFMA(k0, qf0, zero), sA1 = MFMA(k1, qf0, zero);
            f32x4 sA2 = MFMA(k2, qf0, zero), sA3 = MFMA(k3, qf0, zero);
            f32x4 sB0 = MFMA(k0, qf1, zero), sB1 = MFMA(k1, qf1, zero);
            f32x4 sB2 = MFMA(k2, qf1, zero), sB3 = MFMA(k3, qf1, zero);
            Pu PA0, PA1;
            EXPPACK(sA0, sA1, sA2, sA3, PA0, PA1);
            PVSTEP(acc0_0, acc1_0, accl_0, PA0, PA1);
            Pu PB0, PB1;
            EXPPACK(sB0, sB1, sB2, sB3, PB0, PB1);
            PVSTEP(acc0_1, acc1_1, accl_1, PB0, PB1);
        }
        // ---- pair (q2,q3)
        {
            f32x4 sC0 = MFMA(k0, qf2, zero), sC1 = MFMA(k1, qf2, zero);
            f32x4 sC2 = MFMA(k2, qf2, zero), sC3 = MFMA(k3, qf2, zero);
            f32x4 sD0 = MFMA(k0, qf3, zero), sD1 = MFMA(k1, qf3, zero);
            f32x4 sD2 = MFMA(k2, qf3, zero), sD3 = MFMA(k3, qf3, zero);
            Pu PC0, PC1;
            EXPPACK(sC0, sC1, sC2, sC3, PC0, PC1);
            PVSTEP(acc0_2, acc1_2, accl_2, PC0, PC1);
            Pu PD0, PD1;
            EXPPACK(sD0, sD1, sD2, sD3, PD0, PD1);
            PVSTEP(acc0_3, acc1_3, accl_3, PD0, PD1);
        }
        // ds_write staged tile kt+1 (buffer cur^1: its readers sealed by the
        // barrier at end of iteration kt-1)
        if (more) {
            *(uint4*)&ks[cur ^ 1][sw] = krn;
            *(uint4*)&vs[cur ^ 1][sw] = vrn;
        }
        __syncthreads();   // seals: my tile-(kt+1) writes visible; all reads of cur done
    }

    const int b = bh >> 3, hh = bh & 7;
#define WRITE_SLOT(AL, A0, A1, slot) do {                                   \
        const float inv = 1.f / AL[0];                                      \
        const int t = q0 + (slot) * 16 + col;                               \
        short* crow = cp + ((size_t)b * TP + t + 1) * CDIM + hh * DDIM;     \
        uint2 u0 = make_uint2(pk2(A0[0] * inv, A0[1] * inv),                \
                              pk2(A0[2] * inv, A0[3] * inv));               \
        uint2 u1 = make_uint2(pk2(A1[0] * inv, A1[1] * inv),                \
                              pk2(A1[2] * inv, A1[3] * inv));               \
        *(uint2*)(crow + quad * 4)      = u0;                               \
        *(uint2*)(crow + 16 + quad * 4) = u1;                               \
    } while (0)
    WRITE_SLOT(accl_0, acc0_0, acc1_0, 0);
    WRITE_SLOT(accl_1, acc0_1, acc1_1, 1);
    WRITE_SLOT(accl_2, acc0_2, acc1_2, 2);
    WRITE_SLOT(accl_3, acc0_3, acc1_3, 3);
#undef WRITE_SLOT
#undef MFMA
#undef EXPPACK
#undef PVSTEP
}

// ---------------------------------------------------------------------------
extern "C" void kernel_launch(void* const* d_in, const int* in_sizes, int n_in,
                              void* d_out, int out_size, void* d_ws, size_t ws_size,
                              hipStream_t stream) {
    const float* x  = (const float*)d_in[0];
    const float* Wq = (const float*)d_in[1];
    const float* bq = (const float*)d_in[2];
    const float* Wk = (const float*)d_in[3];
    const float* bk = (const float*)d_in[4];
    const float* Wv = (const float*)d_in[5];
    const float* bv = (const float*)d_in[6];
    const float* Wo = (const float*)d_in[7];
    const float* bo = (const float*)d_in[8];
    float* out = (float*)d_out;

    short* p = (short*)d_ws;
    short* xbfp = p; p += (size_t)BDIM * TP * CDIM;        // 4,198,400
    short* cpb  = p; p += (size_t)BDIM * TP * CDIM;        // 4,198,400
    short* qbuf = p; p += (size_t)BDIM * HDIM * TDIM * DDIM; // 4,194,304
    short* kbuf = p; p += (size_t)BDIM * HDIM * TDIM * DDIM;
    short* vt2  = p; p += (size_t)BDIM * HDIM * TDIM * DDIM;
    short* wcat = p; p += 768 * 768;
    short* wot  = p; p += 256 * 768;
    // total ~43.5 MB

    prep_kernel<<<dim3(XBLK + WBLK), 256, 0, stream>>>(x, Wq, Wk, Wv, Wo, xbfp, cpb, wcat, wot);
    gemm_qkv<<<dim3(128, 6), 256, 0, stream>>>(xbfp, wcat, bq, bk, bv, qbuf, kbuf, vt2);
    attn_kernel<<<dim3(64, 8), 256, 0, stream>>>(qbuf, kbuf, vt2, cpb);
    gemm_res<<<dim3(256, 2), 256, 0, stream>>>(cpb, wot, bo, x, out);
}